// Round 2
// baseline (291.137 us; speedup 1.0000x reference)
//
#include <hip/hip_runtime.h>
#include <hip/hip_bf16.h>

typedef __bf16 bf16;
typedef __bf16 bf16x8 __attribute__((ext_vector_type(8)));
typedef float f32x4 __attribute__((ext_vector_type(4)));

#define MFMA16(a, b, c) __builtin_amdgcn_mfma_f32_16x16x32_bf16((a), (b), (c), 0, 0, 0)

// Problem constants
#define BB 2
#define HH 16
#define NN 2048
#define CC 1024
#define HD 64
#define NW (NN / 64)   // 64-key words per row = 32

// Q pre-scale: HD^-0.5 * log2(e), so attention can use exp2 directly.
#define QSCALE 0.1803368867f

// ---------------------------------------------------------------------------
// Per-block dtype detectors (512-word scan, L2-hot, wave-uniform result).
// ---------------------------------------------------------------------------
__device__ __forceinline__ int detect_f32_block(const unsigned int* __restrict__ w) {
    __shared__ int bfc_s, tot_s;
    if (threadIdx.x == 0) { bfc_s = 0; tot_s = 0; }
    __syncthreads();
    int bfc = 0, tot = 0;
    for (int i = threadIdx.x; i < 512; i += blockDim.x) {
        unsigned v = w[i];
        if (v != 0u) {
            tot++;
            unsigned e = (v >> 7) & 0xFFu;
            if (e >= 100u && e <= 140u) bfc++;
        }
    }
    atomicAdd(&bfc_s, bfc); atomicAdd(&tot_s, tot);
    __syncthreads();
    int r = (2 * bfc_s < tot_s) ? 1 : 0;
    __syncthreads();
    return r;
}

// mask element size: int64 -> 8, int32/fp32 -> 4, int16/bf16 -> 2, byte -> 1
__device__ __forceinline__ int detect_esz_block(const unsigned int* __restrict__ w) {
    __shared__ int ok8s, ok4s, ok2s;
    if (threadIdx.x == 0) { ok8s = 1; ok4s = 1; ok2s = 1; }
    __syncthreads();
    int ok8 = 1, ok4 = 1, ok2 = 1;
    for (int i = threadIdx.x; i < 512; i += blockDim.x) {
        unsigned v = w[i];
        if ((i & 1) && v != 0u) ok8 = 0;
        if (!(v == 0u || v == 1u || v == 0x3F800000u)) ok4 = 0;
        unsigned lo = v & 0xFFFFu, hi = v >> 16;
        if (!((lo == 0u || lo == 1u || lo == 0x3F80u) &&
              (hi == 0u || hi == 1u || hi == 0x3F80u))) ok2 = 0;
    }
    if (!ok8) atomicAnd(&ok8s, 0);
    if (!ok4) atomicAnd(&ok4s, 0);
    if (!ok2) atomicAnd(&ok2s, 0);
    __syncthreads();
    int r = ok8s ? 8 : (ok4s ? 4 : (ok2s ? 2 : 1));
    __syncthreads();
    return r;
}

// ---------------------------------------------------------------------------
// Kernel: convert fp32 (or passthrough bf16) -> bf16, 8 elems/thread.
// ---------------------------------------------------------------------------
__global__ __launch_bounds__(256) void cvt_bf16_kernel(const void* __restrict__ src,
                                                       bf16* __restrict__ dst) {
    const int f32 = detect_f32_block((const unsigned int*)src);
    size_t e = ((size_t)blockIdx.x * 256 + threadIdx.x) * 8;
    bf16x8 v;
    if (f32) {
        const f32x4* S = (const f32x4*)((const float*)src + e);
        f32x4 a = S[0], b = S[1];
        v[0] = (bf16)a[0]; v[1] = (bf16)a[1]; v[2] = (bf16)a[2]; v[3] = (bf16)a[3];
        v[4] = (bf16)b[0]; v[5] = (bf16)b[1]; v[6] = (bf16)b[2]; v[7] = (bf16)b[3];
    } else {
        v = *(const bf16x8*)((const bf16*)src + e);
    }
    *(bf16x8*)&dst[e] = v;
}

// ---------------------------------------------------------------------------
// Kernel 0: canonicalize mask to a 64-key bitmask [B, N, N/64] (u64). 1 MB.
// ---------------------------------------------------------------------------
__global__ __launch_bounds__(256) void mask_bits_kernel(const void* __restrict__ maskp,
                                                        unsigned long long* __restrict__ bm) {
    const int esz = detect_esz_block((const unsigned int*)maskp);  // wave-uniform
    const int lane = threadIdx.x & 63;
    const int wave = threadIdx.x >> 6;
    const long wbase = ((long)blockIdx.x * 4 + wave) * 16;          // first word
    for (int i = 0; i < 16; i++) {
        long w = wbase + i;
        long idx = w * 64 + lane;
        bool mk;
        if (esz == 4)      mk = ((const unsigned int*)maskp)[idx] != 0u;
        else if (esz == 2) mk = ((const unsigned short*)maskp)[idx] != 0;
        else if (esz == 8) mk = ((const unsigned long long*)maskp)[idx] != 0ull;
        else               mk = ((const unsigned char*)maskp)[idx] != 0;
        unsigned long long b = __ballot(mk);
        if (lane == 0) bm[w] = b;
    }
}

// ---------------------------------------------------------------------------
// async 16B global -> LDS copy (direct-to-LDS, no VGPR round-trip).
// LDS dest must be wave-uniform base; HW adds lane*16.
// ---------------------------------------------------------------------------
__device__ __forceinline__ void async_cp16(const bf16* g, bf16* l) {
    __builtin_amdgcn_global_load_lds((const __attribute__((address_space(1))) void*)g,
                                     (__attribute__((address_space(3))) void*)l,
                                     16, 0, 0);
}

// ---------------------------------------------------------------------------
// Fast GEMM core (m97 structure): C[128x128] = A[128xK]*B[128xK]^T, K=1024.
// Both operands bf16. Linear [128][64] LDS tiles, global_load_lds width-16,
// 2-barrier K-loop, 16x16x32 MFMA, 4 waves each owning a 64x64 quadrant.
// APERM=1: A addressed as attention output [B,H,N,HD] (head = kt, BK==HD).
// ---------------------------------------------------------------------------
template<int APERM>
__device__ __forceinline__ void gemm_tile_fast(const bf16* __restrict__ Ap,
                                               const bf16* __restrict__ Bp,
                                               int m0, int n0,
                                               bf16* ldsA, bf16* ldsB,
                                               f32x4 acc[4][4]) {
    const int K = 1024;
    const int tid = threadIdx.x, lane = tid & 63, wave = tid >> 6;
    const int l15 = lane & 15, q4 = lane >> 4;
    const int mw = (wave & 1) * 64, nw = (wave >> 1) * 64;

    #pragma unroll
    for (int i = 0; i < 4; i++)
        #pragma unroll
        for (int j = 0; j < 4; j++) {
            f32x4 z = {0.f, 0.f, 0.f, 0.f};
            acc[i][j] = z;
        }

    const int rA = tid >> 3;          // row within 32-row issue group
    const int colc = (tid & 7) << 3;  // col (elems) within 64-wide tile

    for (int kt = 0; kt < 16; ++kt) {
        __syncthreads();   // prior iter's ds_reads complete before overwrite
        #pragma unroll
        for (int i = 0; i < 4; i++) {
            int r = i * 32 + rA;
            size_t ae;
            if (APERM) {
                int m = m0 + r;
                ae = (((size_t)(m >> 11) * HH + kt) * NN + (m & (NN - 1))) * HD + colc;
            } else {
                ae = (size_t)(m0 + r) * K + kt * 64 + colc;
            }
            async_cp16(&Ap[ae], &ldsA[i * 2048 + wave * 512]);
            size_t be = (size_t)(n0 + r) * K + kt * 64 + colc;
            async_cp16(&Bp[be], &ldsB[i * 2048 + wave * 512]);
        }
        __syncthreads();   // vmcnt(0) drain: staged tile visible to all waves
        #pragma unroll
        for (int ks = 0; ks < 2; ks++) {
            bf16x8 af[4], bfr[4];
            #pragma unroll
            for (int i = 0; i < 4; i++)
                af[i] = *(bf16x8*)&ldsA[(mw + i * 16 + l15) * 64 + ks * 32 + q4 * 8];
            #pragma unroll
            for (int j = 0; j < 4; j++)
                bfr[j] = *(bf16x8*)&ldsB[(nw + j * 16 + l15) * 64 + ks * 32 + q4 * 8];
            #pragma unroll
            for (int i = 0; i < 4; i++)
                #pragma unroll
                for (int j = 0; j < 4; j++)
                    acc[i][j] = MFMA16(af[i], bfr[j], acc[i][j]);
        }
    }
}

// ---------------------------------------------------------------------------
// Legacy GEMM core (register-staged, in-loop fp32->bf16): tier-B qkv only.
// ---------------------------------------------------------------------------
__device__ __forceinline__ void gemm_tile(const void* __restrict__ Ap,
                                          const bf16* __restrict__ Bp,
                                          int K, int m0, int n0,
                                          int af32, int aperm,
                                          bf16* ldsA, bf16* ldsB,
                                          f32x4 acc[4][4]) {
    const int tid = threadIdx.x, lane = tid & 63, wave = tid >> 6;
    const int l15 = lane & 15, q4 = lane >> 4;
    const int mw = (wave & 1) * 64, nw = (wave >> 1) * 64;

    #pragma unroll
    for (int i = 0; i < 4; i++)
        #pragma unroll
        for (int j = 0; j < 4; j++) {
            f32x4 z = {0.f, 0.f, 0.f, 0.f};
            acc[i][j] = z;
        }

    const int nkt = K / 64;
    for (int kt = 0; kt < nkt; ++kt) {
        __syncthreads();
        #pragma unroll
        for (int c0 = 0; c0 < 4; c0++) {
            int c = tid + c0 * 256;               // 1024 chunks of 8 elems
            int r = c >> 3, kc = (c & 7) << 3;
            size_t ae;
            if (aperm) {
                int m = m0 + r;
                ae = (((size_t)(m >> 11) * HH + kt) * NN + (m & (NN - 1))) * HD + kc;
            } else {
                ae = (size_t)(m0 + r) * K + kt * 64 + kc;
            }
            bf16x8 av;
            if (af32) {
                const f32x4* Af = (const f32x4*)((const float*)Ap + ae);
                f32x4 a0 = Af[0], a1 = Af[1];
                av[0] = (bf16)a0[0]; av[1] = (bf16)a0[1]; av[2] = (bf16)a0[2]; av[3] = (bf16)a0[3];
                av[4] = (bf16)a1[0]; av[5] = (bf16)a1[1]; av[6] = (bf16)a1[2]; av[7] = (bf16)a1[3];
            } else {
                av = *(const bf16x8*)((const bf16*)Ap + ae);
            }
            *(bf16x8*)&ldsA[r * 72 + kc] = av;
            size_t be = (size_t)(n0 + r) * K + kt * 64 + kc;
            *(bf16x8*)&ldsB[r * 72 + kc] = *(const bf16x8*)&Bp[be];
        }
        __syncthreads();
        #pragma unroll
        for (int ks = 0; ks < 2; ks++) {
            bf16x8 af[4], bfr[4];
            #pragma unroll
            for (int i = 0; i < 4; i++)
                af[i] = *(bf16x8*)&ldsA[(mw + i * 16 + l15) * 72 + ks * 32 + q4 * 8];
            #pragma unroll
            for (int j = 0; j < 4; j++)
                bfr[j] = *(bf16x8*)&ldsB[(nw + j * 16 + l15) * 72 + ks * 32 + q4 * 8];
            #pragma unroll
            for (int i = 0; i < 4; i++)
                #pragma unroll
                for (int j = 0; j < 4; j++)
                    acc[i][j] = MFMA16(af[i], bfr[j], acc[i][j]);
        }
    }
}

// ---------------------------------------------------------------------------
// Kernel 1a: QKV projection, fast path (A pre-converted to bf16).
// ---------------------------------------------------------------------------
__global__ __launch_bounds__(256, 2) void qkv_fast_kernel(const bf16* __restrict__ X16,
                                                          const bf16* __restrict__ Wqkv,
                                                          bf16* __restrict__ Qb,
                                                          bf16* __restrict__ Kb,
                                                          bf16* __restrict__ Vt) {
    __shared__ alignas(16) bf16 ldsA[128 * 64];
    __shared__ alignas(16) bf16 ldsB[128 * 64];
    f32x4 acc[4][4];
    const int m0 = blockIdx.y * 128, n0 = blockIdx.x * 128;
    gemm_tile_fast<0>(X16, Wqkv, m0, n0, ldsA, ldsB, acc);

    const int tid = threadIdx.x, lane = tid & 63, wave = tid >> 6;
    const int l15 = lane & 15, q4 = lane >> 4;
    const int mw = (wave & 1) * 64, nw = (wave >> 1) * 64;
    #pragma unroll
    for (int i = 0; i < 4; i++) {
        #pragma unroll
        for (int j = 0; j < 4; j++) {
            #pragma unroll
            for (int r = 0; r < 4; r++) {
                int m = m0 + mw + i * 16 + q4 * 4 + r;
                int n = n0 + nw + j * 16 + l15;
                int b = m >> 11, nq = m & 2047;
                int which = n >> 10, cc = n & 1023;
                int h = cc >> 6, d = cc & 63;
                float v = acc[i][j][r];
                size_t bh = (size_t)(b * HH + h);
                if (which == 0)
                    Qb[(bh * NN + nq) * HD + d] = (bf16)(v * QSCALE);
                else if (which == 1)
                    Kb[(bh * NN + nq) * HD + d] = (bf16)v;
                else
                    Vt[(bh * HD + d) * NN + nq] = (bf16)v;
            }
        }
    }
}

// ---------------------------------------------------------------------------
// Kernel 1b: QKV projection, legacy path (fp32/bf16 A, reg staging). Tier B.
// ---------------------------------------------------------------------------
__global__ __launch_bounds__(256, 2) void qkv_kernel(const void* __restrict__ X,
                                                     const bf16* __restrict__ Wqkv,
                                                     bf16* __restrict__ Qb,
                                                     bf16* __restrict__ Kb,
                                                     bf16* __restrict__ Vt) {
    __shared__ alignas(16) bf16 ldsA[128 * 72];
    __shared__ alignas(16) bf16 ldsB[128 * 72];
    const int f32 = detect_f32_block((const unsigned int*)X);
    f32x4 acc[4][4];
    const int m0 = blockIdx.y * 128, n0 = blockIdx.x * 128;
    gemm_tile(X, Wqkv, 1024, m0, n0, f32, 0, ldsA, ldsB, acc);

    const int tid = threadIdx.x, lane = tid & 63, wave = tid >> 6;
    const int l15 = lane & 15, q4 = lane >> 4;
    const int mw = (wave & 1) * 64, nw = (wave >> 1) * 64;
    #pragma unroll
    for (int i = 0; i < 4; i++) {
        #pragma unroll
        for (int j = 0; j < 4; j++) {
            #pragma unroll
            for (int r = 0; r < 4; r++) {
                int m = m0 + mw + i * 16 + q4 * 4 + r;
                int n = n0 + nw + j * 16 + l15;
                int b = m >> 11, nq = m & 2047;
                int which = n >> 10, cc = n & 1023;
                int h = cc >> 6, d = cc & 63;
                float v = acc[i][j][r];
                size_t bh = (size_t)(b * HH + h);
                if (which == 0)
                    Qb[(bh * NN + nq) * HD + d] = (bf16)(v * QSCALE);
                else if (which == 1)
                    Kb[(bh * NN + nq) * HD + d] = (bf16)v;
                else
                    Vt[(bh * HD + d) * NN + nq] = (bf16)v;
            }
        }
    }
}

// ---------------------------------------------------------------------------
// Kernel 2: flash attention v7:
//  - T14 async-stage split: K/V/mask loads for tile kt+1 issued BEFORE the
//    compute of tile kt; the next iteration's __syncthreads is the drain.
//    Load latency hides under ~18 MFMA + exp/mask VALU of the current tile.
//  - exp2 direct (Q pre-scaled by log2e at qkv) — drops 16 v_mul/iter.
//  - sj init folded into first MFMA with loop-invariant zero C operand.
//  - XCD-contiguous block swizzle: 64 consecutive blocks (4 bh) per XCD so
//    K/V is single-XCD L2-resident (was: every XCD fetched every bh).
// ---------------------------------------------------------------------------
__global__ __launch_bounds__(512, 2) void attn_kernel(const bf16* __restrict__ Qb,
                                                      const bf16* __restrict__ Kb,
                                                      const bf16* __restrict__ Vt,
                                                      const unsigned long long* __restrict__ bm,
                                                      bf16* __restrict__ Ob) {
    __shared__ alignas(16) bf16 Kt[64 * 72];
    __shared__ alignas(16) bf16 Vs[64 * 72];      // [d][key], stride 72
    __shared__ alignas(16) bf16 Ps[8][16 * 72];   // per-wave P tile (swizzled)

    // XCD swizzle: dispatch i -> XCD i%8; give XCD x logical blocks [x*64,x*64+64)
    const int wg = blockIdx.y * (NN / 128) + blockIdx.x;   // 512 blocks
    const int swzb = (wg & 7) * 64 + (wg >> 3);            // bijective (512%8==0)
    const int bh = swzb >> 4;
    const int qb = (swzb & 15) * 128;
    const int b = bh >> 4;
    const int tid = threadIdx.x, lane = tid & 63, wave = tid >> 6;
    const int l15 = lane & 15, q4 = lane >> 4;

    const bf16* Qp = Qb + (size_t)bh * NN * HD;
    const bf16* Kp = Kb + (size_t)bh * NN * HD;
    const bf16* Vp = Vt + (size_t)bh * HD * NN;

    // staging geometry: 512 chunks of 8 elems = one 64x64 tile
    const int sr = tid >> 3, skc = (tid & 7) << 3;

    // Q fragments (A-layout): m = l15 (q row), k = q4*8..+8
    bf16x8 qf[2];
    {
        int qr = qb + wave * 16 + l15;
        #pragma unroll
        for (int s = 0; s < 2; s++)
            qf[s] = *(const bf16x8*)&Qp[(size_t)qr * HD + s * 32 + q4 * 8];
    }

    // ones B-fragment for the denominator MFMA
    bf16x8 ones;
    #pragma unroll
    for (int i = 0; i < 8; i++) ones[i] = (bf16)1.0f;

    const f32x4 FZ = {0.f, 0.f, 0.f, 0.f};

    f32x4 o[4];
    f32x4 lacc = FZ;
    #pragma unroll
    for (int jd = 0; jd < 4; jd++) o[jd] = FZ;

    // bitmask row pointers: word = (b*NN + q)*NW + kt ; this lane's 4 rows
    const unsigned long long* bmr = bm + ((size_t)b * NN + qb + wave * 16 + q4 * 4) * NW;

    bf16* Pw = &Ps[wave][0];

    // ---- prologue prefetch: tile 0 K/V slices + mask words into registers
    bf16x8 kreg = *(const bf16x8*)&Kp[(size_t)sr * HD + skc];
    bf16x8 vreg = *(const bf16x8*)&Vp[(size_t)sr * NN + skc];
    unsigned long long mw0 = bmr[0 * NW], mw1 = bmr[1 * NW],
                       mw2 = bmr[2 * NW], mw3 = bmr[3 * NW];

    for (int kt = 0; kt < NN / 64; ++kt) {
        __syncthreads();   // all waves done reading prior K/V + own P reads done
        *(bf16x8*)&Kt[sr * 72 + skc] = kreg;
        *(bf16x8*)&Vs[sr * 72 + skc] = vreg;
        __syncthreads();   // staged tile visible

        // capture current mask words before prefetch overwrites them
        unsigned lo[4] = {(unsigned)mw0, (unsigned)mw1, (unsigned)mw2, (unsigned)mw3};
        unsigned hi[4] = {(unsigned)(mw0 >> 32), (unsigned)(mw1 >> 32),
                          (unsigned)(mw2 >> 32), (unsigned)(mw3 >> 32)};

        // ---- T14: issue NEXT tile's global loads now; they complete during
        //      the compute below (drained by next iter's __syncthreads).
        {
            const int ktn = (kt + 1) & (NN / 64 - 1);   // kt=31 reloads tile 0 (unused)
            kreg = *(const bf16x8*)&Kp[(size_t)(ktn * 64 + sr) * HD + skc];
            vreg = *(const bf16x8*)&Vp[(size_t)sr * NN + ktn * 64 + skc];
            mw0 = bmr[0 * NW + ktn]; mw1 = bmr[1 * NW + ktn];
            mw2 = bmr[2 * NW + ktn]; mw3 = bmr[3 * NW + ktn];
        }

        // S = (Q*scale*log2e) K^T : 4 n-subtiles of 16 keys
        f32x4 sj[4];
        #pragma unroll
        for (int j = 0; j < 4; j++) {
            bf16x8 kf0 = *(bf16x8*)&Kt[(j * 16 + l15) * 72 + q4 * 8];
            bf16x8 kf1 = *(bf16x8*)&Kt[(j * 16 + l15) * 72 + 32 + q4 * 8];
            f32x4 t = MFMA16(qf[0], kf0, FZ);
            sj[j] = MFMA16(qf[1], kf1, t);
        }

        // branch-free mask + exp2. C-layout: col = l15, row = q4*4 + r.
        // P store: block kb = 2j + (l15>>3) swizzled by (row>>1)&7.
        const int kbl = l15 >> 3, koff = l15 & 7;
        #pragma unroll
        for (int r = 0; r < 4; r++) {
            const int row = q4 * 4 + r;
            const int swz = (row >> 1) & 7;
            #pragma unroll
            for (int j = 0; j < 4; j++) {
                unsigned w = (j < 2) ? lo[r] : hi[r];
                unsigned bit = (w >> ((j & 1) * 16 + l15)) & 1u;
                float ex = __builtin_amdgcn_exp2f(sj[j][r]);
                float p = bit ? ex : 0.f;
                Pw[row * 72 + ((2 * j + kbl) ^ swz) * 8 + koff] = (bf16)p;
            }
        }

        // O += P V ; lacc += P * 1  (P written+read by SAME wave only)
        #pragma unroll
        for (int ks = 0; ks < 2; ks++) {
            bf16x8 pf = *(bf16x8*)&Pw[l15 * 72 + ((4 * ks + q4) ^ ((l15 >> 1) & 7)) * 8];
            lacc = MFMA16(pf, ones, lacc);
            #pragma unroll
            for (int jd = 0; jd < 4; jd++) {
                bf16x8 vf = *(bf16x8*)&Vs[(jd * 16 + l15) * 72 + ks * 32 + q4 * 8];
                o[jd] = MFMA16(pf, vf, o[jd]);
            }
        }
    }

    // normalize + write (lacc[r] = rowsum for row q4*4+r; no butterfly needed)
    float rl[4];
    #pragma unroll
    for (int r = 0; r < 4; r++) rl[r] = 1.0f / lacc[r];
    #pragma unroll
    for (int jd = 0; jd < 4; jd++) {
        #pragma unroll
        for (int r = 0; r < 4; r++) {
            int q = qb + wave * 16 + q4 * 4 + r;
            int d = jd * 16 + l15;
            Ob[((size_t)bh * NN + q) * HD + d] = (bf16)(o[jd][r] * rl[r]);
        }
    }
}

// ---------------------------------------------------------------------------
// Kernel 3: output projection + bias, fast path (both tiers; A always bf16).
// ---------------------------------------------------------------------------
__global__ __launch_bounds__(256, 2) void proj_fast_kernel(const bf16* __restrict__ Ain,
                                                           const bf16* __restrict__ Wp16,
                                                           const void* __restrict__ biasp,
                                                           void* __restrict__ Outd,
                                                           void* __restrict__ Tmp,
                                                           int direct) {
    __shared__ alignas(16) bf16 ldsA[128 * 64];
    __shared__ alignas(16) bf16 ldsB[128 * 64];
    const int f32 = detect_f32_block((const unsigned int*)biasp);
    f32x4 acc[4][4];
    const int m0 = blockIdx.y * 128, n0 = blockIdx.x * 128;
    gemm_tile_fast<1>(Ain, Wp16, m0, n0, ldsA, ldsB, acc);

    const int tid = threadIdx.x, lane = tid & 63, wave = tid >> 6;
    const int l15 = lane & 15, q4 = lane >> 4;
    const int mw = (wave & 1) * 64, nw = (wave >> 1) * 64;
    #pragma unroll
    for (int i = 0; i < 4; i++) {
        #pragma unroll
        for (int j = 0; j < 4; j++) {
            #pragma unroll
            for (int r = 0; r < 4; r++) {
                int m = m0 + mw + i * 16 + q4 * 4 + r;
                int n = n0 + nw + j * 16 + l15;
                float bv = f32 ? ((const float*)biasp)[n] : (float)((const bf16*)biasp)[n];
                float val = acc[i][j][r] + bv;
                size_t idx = (size_t)m * CC + n;
                if (f32) {
                    if (direct || idx >= (size_t)2097152)   // byte off >= 8MB
                        ((float*)Outd)[idx] = val;
                    else
                        ((float*)Tmp)[idx] = val;
                } else {
                    if (direct) ((bf16*)Outd)[idx] = (bf16)val;
                    else        ((bf16*)Tmp)[idx] = (bf16)val;
                }
            }
        }
    }
}

// ---------------------------------------------------------------------------
// Memory map (fp32 output established => d_out = 16.78 MB):
//  d_out: [0, 8.39M)        Q scratch (tier B: attention O in-place)
//         [8.39M, 14.68M)   W_qkv bf16 (dead after qkv)
//         [14.68M, 15.73M)  key bitmask (dead after attn)
//  ws:    [0, 8.39M)        Kb (tier B: proj low-half staging after attn)
//         [8.39M, 16.78M)   Vt; after attn: Wp16 bf16 (2.1 MB) at 8.39M
//         tier A adds @16.78M: X16 bf16 (dead after qkv) then Ob (attn out)
// ---------------------------------------------------------------------------
extern "C" void kernel_launch(void* const* d_in, const int* in_sizes, int n_in,
                              void* d_out, int out_size, void* d_ws, size_t ws_size,
                              hipStream_t stream) {
    const void* x    = d_in[0];
    const void* mask = d_in[1];
    const void* Wqkv = d_in[2];
    const void* Wp   = d_in[3];
    const void* bias = d_in[4];

    char* ws = (char*)d_ws;
    const size_t QS  = (size_t)BB * HH * NN * HD;     // 4,194,304 elems
    const size_t QSB = QS * sizeof(bf16);             // 8,388,608 bytes
    bf16* Qb   = (bf16*)d_out;
    bf16* W16  = (bf16*)((char*)d_out + QSB);                      // 6.29 MB
    unsigned long long* bm = (unsigned long long*)((char*)d_out + QSB + 3 * CC * CC * 2);
    bf16* Kb   = (bf16*)ws;
    bf16* Vt   = (bf16*)(ws + QSB);
    bf16* Wp16 = (bf16*)(ws + QSB);                                // after attn (Vt dead)

    mask_bits_kernel<<<2048, 256, 0, stream>>>(mask, bm);
    cvt_bf16_kernel<<<3 * CC * CC / (256 * 8), 256, 0, stream>>>(Wqkv, W16);

    if (ws_size >= 3 * QSB) {
        // Fast qkv: pre-convert X to bf16 in the (not-yet-live) Ob slot.
        bf16* X16 = (bf16*)(ws + 2 * QSB);
        cvt_bf16_kernel<<<(BB * NN * CC) / (256 * 8), 256, 0, stream>>>(x, X16);
        qkv_fast_kernel<<<dim3(3072 / 128, 4096 / 128), 256, 0, stream>>>(X16, W16, Qb, Kb, Vt);
        bf16* Ob = (bf16*)(ws + 2 * QSB);   // reuses X16 slot (X16 dead)
        attn_kernel<<<dim3(NN / 128, BB * HH), 512, 0, stream>>>(Qb, Kb, Vt, bm, Ob);
        cvt_bf16_kernel<<<CC * CC / (256 * 8), 256, 0, stream>>>(Wp, Wp16);
        proj_fast_kernel<<<dim3(1024 / 128, 4096 / 128), 256, 0, stream>>>(Ob, Wp16, bias, d_out, d_out, 1);
    } else {
        qkv_kernel<<<dim3(3072 / 128, 4096 / 128), 256, 0, stream>>>(x, W16, Qb, Kb, Vt);
        attn_kernel<<<dim3(NN / 128, BB * HH), 512, 0, stream>>>(Qb, Kb, Vt, bm, Qb);
        cvt_bf16_kernel<<<CC * CC / (256 * 8), 256, 0, stream>>>(Wp, Wp16);
        proj_fast_kernel<<<dim3(1024 / 128, 4096 / 128), 256, 0, stream>>>(Qb, Wp16, bias, d_out, ws, 0);
        hipMemcpyAsync(d_out, ws, QSB, hipMemcpyDeviceToDevice, stream);
    }
}

// Round 3
// 281.487 us; speedup vs baseline: 1.0343x; 1.0343x over previous
//
#include <hip/hip_runtime.h>
#include <hip/hip_bf16.h>

typedef __bf16 bf16;
typedef __bf16 bf16x8 __attribute__((ext_vector_type(8)));
typedef float f32x4 __attribute__((ext_vector_type(4)));

#define MFMA16(a, b, c) __builtin_amdgcn_mfma_f32_16x16x32_bf16((a), (b), (c), 0, 0, 0)

// Problem constants
#define BB 2
#define HH 16
#define NN 2048
#define CC 1024
#define HD 64
#define NW (NN / 64)   // 64-key words per row = 32

// Q pre-scale: HD^-0.5 * log2(e), so attention can use exp2 directly.
#define QSCALE 0.1803368867f

// ---------------------------------------------------------------------------
// Per-block dtype detectors (512-word scan, L2-hot, wave-uniform result).
// ---------------------------------------------------------------------------
__device__ __forceinline__ int detect_f32_block(const unsigned int* __restrict__ w) {
    __shared__ int bfc_s, tot_s;
    if (threadIdx.x == 0) { bfc_s = 0; tot_s = 0; }
    __syncthreads();
    int bfc = 0, tot = 0;
    for (int i = threadIdx.x; i < 512; i += blockDim.x) {
        unsigned v = w[i];
        if (v != 0u) {
            tot++;
            unsigned e = (v >> 7) & 0xFFu;
            if (e >= 100u && e <= 140u) bfc++;
        }
    }
    atomicAdd(&bfc_s, bfc); atomicAdd(&tot_s, tot);
    __syncthreads();
    int r = (2 * bfc_s < tot_s) ? 1 : 0;
    __syncthreads();
    return r;
}

// mask element size: int64 -> 8, int32/fp32 -> 4, int16/bf16 -> 2, byte -> 1
__device__ __forceinline__ int detect_esz_block(const unsigned int* __restrict__ w) {
    __shared__ int ok8s, ok4s, ok2s;
    if (threadIdx.x == 0) { ok8s = 1; ok4s = 1; ok2s = 1; }
    __syncthreads();
    int ok8 = 1, ok4 = 1, ok2 = 1;
    for (int i = threadIdx.x; i < 512; i += blockDim.x) {
        unsigned v = w[i];
        if ((i & 1) && v != 0u) ok8 = 0;
        if (!(v == 0u || v == 1u || v == 0x3F800000u)) ok4 = 0;
        unsigned lo = v & 0xFFFFu, hi = v >> 16;
        if (!((lo == 0u || lo == 1u || lo == 0x3F80u) &&
              (hi == 0u || hi == 1u || hi == 0x3F80u))) ok2 = 0;
    }
    if (!ok8) atomicAnd(&ok8s, 0);
    if (!ok4) atomicAnd(&ok4s, 0);
    if (!ok2) atomicAnd(&ok2s, 0);
    __syncthreads();
    int r = ok8s ? 8 : (ok4s ? 4 : (ok2s ? 2 : 1));
    __syncthreads();
    return r;
}

// ---------------------------------------------------------------------------
// Kernel: convert fp32 (or passthrough bf16) -> bf16, 8 elems/thread.
// ---------------------------------------------------------------------------
__global__ __launch_bounds__(256) void cvt_bf16_kernel(const void* __restrict__ src,
                                                       bf16* __restrict__ dst) {
    const int f32 = detect_f32_block((const unsigned int*)src);
    size_t e = ((size_t)blockIdx.x * 256 + threadIdx.x) * 8;
    bf16x8 v;
    if (f32) {
        const f32x4* S = (const f32x4*)((const float*)src + e);
        f32x4 a = S[0], b = S[1];
        v[0] = (bf16)a[0]; v[1] = (bf16)a[1]; v[2] = (bf16)a[2]; v[3] = (bf16)a[3];
        v[4] = (bf16)b[0]; v[5] = (bf16)b[1]; v[6] = (bf16)b[2]; v[7] = (bf16)b[3];
    } else {
        v = *(const bf16x8*)((const bf16*)src + e);
    }
    *(bf16x8*)&dst[e] = v;
}

// ---------------------------------------------------------------------------
// Kernel 0: canonicalize mask to a 64-key bitmask [B, N, N/64] (u64). 1 MB.
// ---------------------------------------------------------------------------
__global__ __launch_bounds__(256) void mask_bits_kernel(const void* __restrict__ maskp,
                                                        unsigned long long* __restrict__ bm) {
    const int esz = detect_esz_block((const unsigned int*)maskp);  // wave-uniform
    const int lane = threadIdx.x & 63;
    const int wave = threadIdx.x >> 6;
    const long wbase = ((long)blockIdx.x * 4 + wave) * 16;          // first word
    for (int i = 0; i < 16; i++) {
        long w = wbase + i;
        long idx = w * 64 + lane;
        bool mk;
        if (esz == 4)      mk = ((const unsigned int*)maskp)[idx] != 0u;
        else if (esz == 2) mk = ((const unsigned short*)maskp)[idx] != 0;
        else if (esz == 8) mk = ((const unsigned long long*)maskp)[idx] != 0ull;
        else               mk = ((const unsigned char*)maskp)[idx] != 0;
        unsigned long long b = __ballot(mk);
        if (lane == 0) bm[w] = b;
    }
}

// ---------------------------------------------------------------------------
// async 16B global -> LDS copy (direct-to-LDS, no VGPR round-trip).
// LDS dest must be wave-uniform base; HW adds lane*16.
// ---------------------------------------------------------------------------
__device__ __forceinline__ void async_cp16(const bf16* g, bf16* l) {
    __builtin_amdgcn_global_load_lds((const __attribute__((address_space(1))) void*)g,
                                     (__attribute__((address_space(3))) void*)l,
                                     16, 0, 0);
}

// ---------------------------------------------------------------------------
// Fast GEMM core (m97 structure): C[128x128] = A[128xK]*B[128xK]^T, K=1024.
// ---------------------------------------------------------------------------
template<int APERM>
__device__ __forceinline__ void gemm_tile_fast(const bf16* __restrict__ Ap,
                                               const bf16* __restrict__ Bp,
                                               int m0, int n0,
                                               bf16* ldsA, bf16* ldsB,
                                               f32x4 acc[4][4]) {
    const int K = 1024;
    const int tid = threadIdx.x, lane = tid & 63, wave = tid >> 6;
    const int l15 = lane & 15, q4 = lane >> 4;
    const int mw = (wave & 1) * 64, nw = (wave >> 1) * 64;

    #pragma unroll
    for (int i = 0; i < 4; i++)
        #pragma unroll
        for (int j = 0; j < 4; j++) {
            f32x4 z = {0.f, 0.f, 0.f, 0.f};
            acc[i][j] = z;
        }

    const int rA = tid >> 3;          // row within 32-row issue group
    const int colc = (tid & 7) << 3;  // col (elems) within 64-wide tile

    for (int kt = 0; kt < 16; ++kt) {
        __syncthreads();   // prior iter's ds_reads complete before overwrite
        #pragma unroll
        for (int i = 0; i < 4; i++) {
            int r = i * 32 + rA;
            size_t ae;
            if (APERM) {
                int m = m0 + r;
                ae = (((size_t)(m >> 11) * HH + kt) * NN + (m & (NN - 1))) * HD + colc;
            } else {
                ae = (size_t)(m0 + r) * K + kt * 64 + colc;
            }
            async_cp16(&Ap[ae], &ldsA[i * 2048 + wave * 512]);
            size_t be = (size_t)(n0 + r) * K + kt * 64 + colc;
            async_cp16(&Bp[be], &ldsB[i * 2048 + wave * 512]);
        }
        __syncthreads();   // vmcnt(0) drain: staged tile visible to all waves
        #pragma unroll
        for (int ks = 0; ks < 2; ks++) {
            bf16x8 af[4], bfr[4];
            #pragma unroll
            for (int i = 0; i < 4; i++)
                af[i] = *(bf16x8*)&ldsA[(mw + i * 16 + l15) * 64 + ks * 32 + q4 * 8];
            #pragma unroll
            for (int j = 0; j < 4; j++)
                bfr[j] = *(bf16x8*)&ldsB[(nw + j * 16 + l15) * 64 + ks * 32 + q4 * 8];
            #pragma unroll
            for (int i = 0; i < 4; i++)
                #pragma unroll
                for (int j = 0; j < 4; j++)
                    acc[i][j] = MFMA16(af[i], bfr[j], acc[i][j]);
        }
    }
}

// ---------------------------------------------------------------------------
// Legacy GEMM core (register-staged, in-loop fp32->bf16): tier-B qkv only.
// ---------------------------------------------------------------------------
__device__ __forceinline__ void gemm_tile(const void* __restrict__ Ap,
                                          const bf16* __restrict__ Bp,
                                          int K, int m0, int n0,
                                          int af32, int aperm,
                                          bf16* ldsA, bf16* ldsB,
                                          f32x4 acc[4][4]) {
    const int tid = threadIdx.x, lane = tid & 63, wave = tid >> 6;
    const int l15 = lane & 15, q4 = lane >> 4;
    const int mw = (wave & 1) * 64, nw = (wave >> 1) * 64;

    #pragma unroll
    for (int i = 0; i < 4; i++)
        #pragma unroll
        for (int j = 0; j < 4; j++) {
            f32x4 z = {0.f, 0.f, 0.f, 0.f};
            acc[i][j] = z;
        }

    const int nkt = K / 64;
    for (int kt = 0; kt < nkt; ++kt) {
        __syncthreads();
        #pragma unroll
        for (int c0 = 0; c0 < 4; c0++) {
            int c = tid + c0 * 256;               // 1024 chunks of 8 elems
            int r = c >> 3, kc = (c & 7) << 3;
            size_t ae;
            if (aperm) {
                int m = m0 + r;
                ae = (((size_t)(m >> 11) * HH + kt) * NN + (m & (NN - 1))) * HD + kc;
            } else {
                ae = (size_t)(m0 + r) * K + kt * 64 + kc;
            }
            bf16x8 av;
            if (af32) {
                const f32x4* Af = (const f32x4*)((const float*)Ap + ae);
                f32x4 a0 = Af[0], a1 = Af[1];
                av[0] = (bf16)a0[0]; av[1] = (bf16)a0[1]; av[2] = (bf16)a0[2]; av[3] = (bf16)a0[3];
                av[4] = (bf16)a1[0]; av[5] = (bf16)a1[1]; av[6] = (bf16)a1[2]; av[7] = (bf16)a1[3];
            } else {
                av = *(const bf16x8*)((const bf16*)Ap + ae);
            }
            *(bf16x8*)&ldsA[r * 72 + kc] = av;
            size_t be = (size_t)(n0 + r) * K + kt * 64 + kc;
            *(bf16x8*)&ldsB[r * 72 + kc] = *(const bf16x8*)&Bp[be];
        }
        __syncthreads();
        #pragma unroll
        for (int ks = 0; ks < 2; ks++) {
            bf16x8 af[4], bfr[4];
            #pragma unroll
            for (int i = 0; i < 4; i++)
                af[i] = *(bf16x8*)&ldsA[(mw + i * 16 + l15) * 72 + ks * 32 + q4 * 8];
            #pragma unroll
            for (int j = 0; j < 4; j++)
                bfr[j] = *(bf16x8*)&ldsB[(nw + j * 16 + l15) * 72 + ks * 32 + q4 * 8];
            #pragma unroll
            for (int i = 0; i < 4; i++)
                #pragma unroll
                for (int j = 0; j < 4; j++)
                    acc[i][j] = MFMA16(af[i], bfr[j], acc[i][j]);
        }
    }
}

// ---------------------------------------------------------------------------
// Kernel 1a: QKV projection, fast path (A pre-converted to bf16).
// ---------------------------------------------------------------------------
__global__ __launch_bounds__(256, 2) void qkv_fast_kernel(const bf16* __restrict__ X16,
                                                          const bf16* __restrict__ Wqkv,
                                                          bf16* __restrict__ Qb,
                                                          bf16* __restrict__ Kb,
                                                          bf16* __restrict__ Vt) {
    __shared__ alignas(16) bf16 ldsA[128 * 64];
    __shared__ alignas(16) bf16 ldsB[128 * 64];
    f32x4 acc[4][4];
    const int m0 = blockIdx.y * 128, n0 = blockIdx.x * 128;
    gemm_tile_fast<0>(X16, Wqkv, m0, n0, ldsA, ldsB, acc);

    const int tid = threadIdx.x, lane = tid & 63, wave = tid >> 6;
    const int l15 = lane & 15, q4 = lane >> 4;
    const int mw = (wave & 1) * 64, nw = (wave >> 1) * 64;
    #pragma unroll
    for (int i = 0; i < 4; i++) {
        #pragma unroll
        for (int j = 0; j < 4; j++) {
            #pragma unroll
            for (int r = 0; r < 4; r++) {
                int m = m0 + mw + i * 16 + q4 * 4 + r;
                int n = n0 + nw + j * 16 + l15;
                int b = m >> 11, nq = m & 2047;
                int which = n >> 10, cc = n & 1023;
                int h = cc >> 6, d = cc & 63;
                float v = acc[i][j][r];
                size_t bh = (size_t)(b * HH + h);
                if (which == 0)
                    Qb[(bh * NN + nq) * HD + d] = (bf16)(v * QSCALE);
                else if (which == 1)
                    Kb[(bh * NN + nq) * HD + d] = (bf16)v;
                else
                    Vt[(bh * HD + d) * NN + nq] = (bf16)v;
            }
        }
    }
}

// ---------------------------------------------------------------------------
// Kernel 1b: QKV projection, legacy path (fp32/bf16 A, reg staging). Tier B.
// ---------------------------------------------------------------------------
__global__ __launch_bounds__(256, 2) void qkv_kernel(const void* __restrict__ X,
                                                     const bf16* __restrict__ Wqkv,
                                                     bf16* __restrict__ Qb,
                                                     bf16* __restrict__ Kb,
                                                     bf16* __restrict__ Vt) {
    __shared__ alignas(16) bf16 ldsA[128 * 72];
    __shared__ alignas(16) bf16 ldsB[128 * 72];
    const int f32 = detect_f32_block((const unsigned int*)X);
    f32x4 acc[4][4];
    const int m0 = blockIdx.y * 128, n0 = blockIdx.x * 128;
    gemm_tile(X, Wqkv, 1024, m0, n0, f32, 0, ldsA, ldsB, acc);

    const int tid = threadIdx.x, lane = tid & 63, wave = tid >> 6;
    const int l15 = lane & 15, q4 = lane >> 4;
    const int mw = (wave & 1) * 64, nw = (wave >> 1) * 64;
    #pragma unroll
    for (int i = 0; i < 4; i++) {
        #pragma unroll
        for (int j = 0; j < 4; j++) {
            #pragma unroll
            for (int r = 0; r < 4; r++) {
                int m = m0 + mw + i * 16 + q4 * 4 + r;
                int n = n0 + nw + j * 16 + l15;
                int b = m >> 11, nq = m & 2047;
                int which = n >> 10, cc = n & 1023;
                int h = cc >> 6, d = cc & 63;
                float v = acc[i][j][r];
                size_t bh = (size_t)(b * HH + h);
                if (which == 0)
                    Qb[(bh * NN + nq) * HD + d] = (bf16)(v * QSCALE);
                else if (which == 1)
                    Kb[(bh * NN + nq) * HD + d] = (bf16)v;
                else
                    Vt[(bh * HD + d) * NN + nq] = (bf16)v;
            }
        }
    }
}

// ---------------------------------------------------------------------------
// Kernel 2: flash attention v8 — LDS-bandwidth restructure:
//  - BQ=256: 8 waves x 32 q-rows each. Every K/V LDS fragment read now feeds
//    TWO MFMAs (row-halves h=0/1), halving LDS bytes per q-row (was: each
//    wave re-read the full 16KB K+V tile for only 16 rows).
//  - Double-buffered Kt/Vs: ONE barrier per kt-iteration (was 2).
//  - Grid 256 blocks = 1/CU; XCD swizzle: 32 contiguous blocks (4 bh) / XCD.
//  - T14 reg prefetch of next K/V slice + mask words kept.
//  - s_setprio(1) around the PV MFMA cluster (T5).
// ---------------------------------------------------------------------------
__global__ __launch_bounds__(512, 2) void attn_kernel(const bf16* __restrict__ Qb,
                                                      const bf16* __restrict__ Kb,
                                                      const bf16* __restrict__ Vt,
                                                      const unsigned long long* __restrict__ bm,
                                                      bf16* __restrict__ Ob) {
    __shared__ alignas(16) bf16 Kt[2][64 * 72];
    __shared__ alignas(16) bf16 Vs[2][64 * 72];    // [d][key], stride 72
    __shared__ alignas(16) bf16 Ps[8][32 * 72];    // per-wave P tile (swizzled)

    // XCD swizzle: 256 blocks; XCD x gets logical blocks [x*32, x*32+32) = 4 bh
    const int wg = blockIdx.y * (NN / 256) + blockIdx.x;   // 256 blocks
    const int swzb = (wg & 7) * 32 + (wg >> 3);            // bijective (256%8==0)
    const int bh = swzb >> 3;
    const int qb = (swzb & 7) * 256;
    const int b = bh >> 4;
    const int tid = threadIdx.x, lane = tid & 63, wave = tid >> 6;
    const int l15 = lane & 15, q4 = lane >> 4;

    const bf16* Qp = Qb + (size_t)bh * NN * HD;
    const bf16* Kp = Kb + (size_t)bh * NN * HD;
    const bf16* Vp = Vt + (size_t)bh * HD * NN;

    // staging geometry: 512 chunks of 8 elems = one 64x64 tile
    const int sr = tid >> 3, skc = (tid & 7) << 3;

    // Q fragments for both 16-row halves: rows qrb + h*16 + l15
    const int qrb = qb + wave * 32;
    bf16x8 qf[2][2];
    #pragma unroll
    for (int h = 0; h < 2; h++)
        #pragma unroll
        for (int s = 0; s < 2; s++)
            qf[h][s] = *(const bf16x8*)&Qp[(size_t)(qrb + h * 16 + l15) * HD + s * 32 + q4 * 8];

    // ones B-fragment for the denominator MFMA
    bf16x8 ones;
    #pragma unroll
    for (int i = 0; i < 8; i++) ones[i] = (bf16)1.0f;

    const f32x4 FZ = {0.f, 0.f, 0.f, 0.f};

    f32x4 o[2][4];
    f32x4 lacc[2] = {FZ, FZ};
    #pragma unroll
    for (int h = 0; h < 2; h++)
        #pragma unroll
        for (int jd = 0; jd < 4; jd++) o[h][jd] = FZ;

    // bitmask: this lane's rows are qrb + h*16 + q4*4 + r
    const unsigned long long* bmr = bm + ((size_t)b * NN + qrb + q4 * 4) * NW;

    bf16* Pw = &Ps[wave][0];

    // ---- prologue prefetch: tile 0 K/V slices + mask words into registers
    bf16x8 kreg = *(const bf16x8*)&Kp[(size_t)sr * HD + skc];
    bf16x8 vreg = *(const bf16x8*)&Vp[(size_t)sr * NN + skc];
    unsigned long long mwreg[2][4];
    #pragma unroll
    for (int h = 0; h < 2; h++)
        #pragma unroll
        for (int r = 0; r < 4; r++)
            mwreg[h][r] = bmr[(h * 16 + r) * NW];

    for (int kt = 0; kt < NN / 64; ++kt) {
        bf16* KtC = &Kt[kt & 1][0];
        bf16* VsC = &Vs[kt & 1][0];
        // stage this tile (regs -> LDS); readers of this buffer from iter
        // kt-2 are separated by barrier(kt-1): single barrier per iter safe.
        *(bf16x8*)&KtC[sr * 72 + skc] = kreg;
        *(bf16x8*)&VsC[sr * 72 + skc] = vreg;
        __syncthreads();

        // capture current mask words before prefetch overwrites them
        unsigned lo[2][4], hi[2][4];
        #pragma unroll
        for (int h = 0; h < 2; h++)
            #pragma unroll
            for (int r = 0; r < 4; r++) {
                lo[h][r] = (unsigned)mwreg[h][r];
                hi[h][r] = (unsigned)(mwreg[h][r] >> 32);
            }

        // ---- T14: issue NEXT tile's global loads now; latency hides under
        //      this tile's MFMA+VALU; consumed at next iter's stage writes.
        {
            const int ktn = (kt + 1) & (NN / 64 - 1);   // kt=31 reloads tile 0 (unused)
            kreg = *(const bf16x8*)&Kp[(size_t)(ktn * 64 + sr) * HD + skc];
            vreg = *(const bf16x8*)&Vp[(size_t)sr * NN + ktn * 64 + skc];
            #pragma unroll
            for (int h = 0; h < 2; h++)
                #pragma unroll
                for (int r = 0; r < 4; r++)
                    mwreg[h][r] = bmr[(h * 16 + r) * NW + ktn];
        }

        // S = (Q*scale*log2e) K^T for both halves; each kf read feeds 2 MFMAs
        f32x4 sj[2][4];
        #pragma unroll
        for (int j = 0; j < 4; j++) {
            bf16x8 kf0 = *(bf16x8*)&KtC[(j * 16 + l15) * 72 + q4 * 8];
            sj[0][j] = MFMA16(qf[0][0], kf0, FZ);
            sj[1][j] = MFMA16(qf[1][0], kf0, FZ);
            bf16x8 kf1 = *(bf16x8*)&KtC[(j * 16 + l15) * 72 + 32 + q4 * 8];
            sj[0][j] = MFMA16(qf[0][1], kf1, sj[0][j]);
            sj[1][j] = MFMA16(qf[1][1], kf1, sj[1][j]);
        }

        // branch-free mask + exp2. C-layout: col = l15, row(h) = h*16+q4*4+r.
        const int kbl = l15 >> 3, koff = l15 & 7;
        #pragma unroll
        for (int h = 0; h < 2; h++) {
            #pragma unroll
            for (int r = 0; r < 4; r++) {
                const int row = h * 16 + q4 * 4 + r;
                const int swz = (row >> 1) & 7;
                #pragma unroll
                for (int j = 0; j < 4; j++) {
                    unsigned w = (j < 2) ? lo[h][r] : hi[h][r];
                    unsigned bit = (w >> ((j & 1) * 16 + l15)) & 1u;
                    float ex = __builtin_amdgcn_exp2f(sj[h][j][r]);
                    float p = bit ? ex : 0.f;
                    Pw[row * 72 + ((2 * j + kbl) ^ swz) * 8 + koff] = (bf16)p;
                }
            }
        }

        // O += P V ; lacc += P * 1. Each vf read feeds both halves' MFMAs.
        __builtin_amdgcn_s_setprio(1);
        #pragma unroll
        for (int ks = 0; ks < 2; ks++) {
            const int psw = ((4 * ks + q4) ^ ((l15 >> 1) & 7)) * 8;
            bf16x8 pf0 = *(bf16x8*)&Pw[l15 * 72 + psw];
            bf16x8 pf1 = *(bf16x8*)&Pw[(16 + l15) * 72 + psw];
            lacc[0] = MFMA16(pf0, ones, lacc[0]);
            lacc[1] = MFMA16(pf1, ones, lacc[1]);
            #pragma unroll
            for (int jd = 0; jd < 4; jd++) {
                bf16x8 vf = *(bf16x8*)&VsC[(jd * 16 + l15) * 72 + ks * 32 + q4 * 8];
                o[0][jd] = MFMA16(pf0, vf, o[0][jd]);
                o[1][jd] = MFMA16(pf1, vf, o[1][jd]);
            }
        }
        __builtin_amdgcn_s_setprio(0);
    }

    // normalize + write (lacc[h][r] = rowsum for row h*16+q4*4+r)
    #pragma unroll
    for (int h = 0; h < 2; h++) {
        float rl[4];
        #pragma unroll
        for (int r = 0; r < 4; r++) rl[r] = 1.0f / lacc[h][r];
        #pragma unroll
        for (int jd = 0; jd < 4; jd++) {
            #pragma unroll
            for (int r = 0; r < 4; r++) {
                int q = qrb + h * 16 + q4 * 4 + r;
                int d = jd * 16 + l15;
                Ob[((size_t)bh * NN + q) * HD + d] = (bf16)(o[h][jd][r] * rl[r]);
            }
        }
    }
}

// ---------------------------------------------------------------------------
// Kernel 3: output projection + bias, fast path (both tiers; A always bf16).
// ---------------------------------------------------------------------------
__global__ __launch_bounds__(256, 2) void proj_fast_kernel(const bf16* __restrict__ Ain,
                                                           const bf16* __restrict__ Wp16,
                                                           const void* __restrict__ biasp,
                                                           void* __restrict__ Outd,
                                                           void* __restrict__ Tmp,
                                                           int direct) {
    __shared__ alignas(16) bf16 ldsA[128 * 64];
    __shared__ alignas(16) bf16 ldsB[128 * 64];
    const int f32 = detect_f32_block((const unsigned int*)biasp);
    f32x4 acc[4][4];
    const int m0 = blockIdx.y * 128, n0 = blockIdx.x * 128;
    gemm_tile_fast<1>(Ain, Wp16, m0, n0, ldsA, ldsB, acc);

    const int tid = threadIdx.x, lane = tid & 63, wave = tid >> 6;
    const int l15 = lane & 15, q4 = lane >> 4;
    const int mw = (wave & 1) * 64, nw = (wave >> 1) * 64;
    #pragma unroll
    for (int i = 0; i < 4; i++) {
        #pragma unroll
        for (int j = 0; j < 4; j++) {
            #pragma unroll
            for (int r = 0; r < 4; r++) {
                int m = m0 + mw + i * 16 + q4 * 4 + r;
                int n = n0 + nw + j * 16 + l15;
                float bv = f32 ? ((const float*)biasp)[n] : (float)((const bf16*)biasp)[n];
                float val = acc[i][j][r] + bv;
                size_t idx = (size_t)m * CC + n;
                if (f32) {
                    if (direct || idx >= (size_t)2097152)   // byte off >= 8MB
                        ((float*)Outd)[idx] = val;
                    else
                        ((float*)Tmp)[idx] = val;
                } else {
                    if (direct) ((bf16*)Outd)[idx] = (bf16)val;
                    else        ((bf16*)Tmp)[idx] = (bf16)val;
                }
            }
        }
    }
}

// ---------------------------------------------------------------------------
// Memory map (fp32 output established => d_out = 16.78 MB):
//  d_out: [0, 8.39M)        Q scratch (tier B: attention O in-place)
//         [8.39M, 14.68M)   W_qkv bf16 (dead after qkv)
//         [14.68M, 15.73M)  key bitmask (dead after attn)
//  ws:    [0, 8.39M)        Kb (tier B: proj low-half staging after attn)
//         [8.39M, 16.78M)   Vt; after attn: Wp16 bf16 (2.1 MB) at 8.39M
//         tier A adds @16.78M: X16 bf16 (dead after qkv) then Ob (attn out)
// ---------------------------------------------------------------------------
extern "C" void kernel_launch(void* const* d_in, const int* in_sizes, int n_in,
                              void* d_out, int out_size, void* d_ws, size_t ws_size,
                              hipStream_t stream) {
    const void* x    = d_in[0];
    const void* mask = d_in[1];
    const void* Wqkv = d_in[2];
    const void* Wp   = d_in[3];
    const void* bias = d_in[4];

    char* ws = (char*)d_ws;
    const size_t QS  = (size_t)BB * HH * NN * HD;     // 4,194,304 elems
    const size_t QSB = QS * sizeof(bf16);             // 8,388,608 bytes
    bf16* Qb   = (bf16*)d_out;
    bf16* W16  = (bf16*)((char*)d_out + QSB);                      // 6.29 MB
    unsigned long long* bm = (unsigned long long*)((char*)d_out + QSB + 3 * CC * CC * 2);
    bf16* Kb   = (bf16*)ws;
    bf16* Vt   = (bf16*)(ws + QSB);
    bf16* Wp16 = (bf16*)(ws + QSB);                                // after attn (Vt dead)

    mask_bits_kernel<<<2048, 256, 0, stream>>>(mask, bm);
    cvt_bf16_kernel<<<3 * CC * CC / (256 * 8), 256, 0, stream>>>(Wqkv, W16);

    if (ws_size >= 3 * QSB) {
        // Fast qkv: pre-convert X to bf16 in the (not-yet-live) Ob slot.
        bf16* X16 = (bf16*)(ws + 2 * QSB);
        cvt_bf16_kernel<<<(BB * NN * CC) / (256 * 8), 256, 0, stream>>>(x, X16);
        qkv_fast_kernel<<<dim3(3072 / 128, 4096 / 128), 256, 0, stream>>>(X16, W16, Qb, Kb, Vt);
        bf16* Ob = (bf16*)(ws + 2 * QSB);   // reuses X16 slot (X16 dead)
        attn_kernel<<<dim3(NN / 256, BB * HH), 512, 0, stream>>>(Qb, Kb, Vt, bm, Ob);
        cvt_bf16_kernel<<<CC * CC / (256 * 8), 256, 0, stream>>>(Wp, Wp16);
        proj_fast_kernel<<<dim3(1024 / 128, 4096 / 128), 256, 0, stream>>>(Ob, Wp16, bias, d_out, d_out, 1);
    } else {
        qkv_kernel<<<dim3(3072 / 128, 4096 / 128), 256, 0, stream>>>(x, W16, Qb, Kb, Vt);
        attn_kernel<<<dim3(NN / 256, BB * HH), 512, 0, stream>>>(Qb, Kb, Vt, bm, Qb);
        cvt_bf16_kernel<<<CC * CC / (256 * 8), 256, 0, stream>>>(Wp, Wp16);
        proj_fast_kernel<<<dim3(1024 / 128, 4096 / 128), 256, 0, stream>>>(Qb, Wp16, bias, d_out, ws, 0);
        hipMemcpyAsync(d_out, ws, QSB, hipMemcpyDeviceToDevice, stream);
    }
}

// Round 5
// 278.953 us; speedup vs baseline: 1.0437x; 1.0091x over previous
//
#include <hip/hip_runtime.h>
#include <hip/hip_bf16.h>

typedef __bf16 bf16;
typedef __bf16 bf16x4 __attribute__((ext_vector_type(4)));
typedef __bf16 bf16x8 __attribute__((ext_vector_type(8)));
typedef float f32x4 __attribute__((ext_vector_type(4)));

#define MFMA16(a, b, c) __builtin_amdgcn_mfma_f32_16x16x32_bf16((a), (b), (c), 0, 0, 0)

// Problem constants
#define BB 2
#define HH 16
#define NN 2048
#define CC 1024
#define HD 64
#define NW (NN / 64)   // 64-key words per row = 32

// Q pre-scale: HD^-0.5 * log2(e), so attention can use exp2 directly.
#define QSCALE 0.1803368867f

// ---------------------------------------------------------------------------
// Per-block dtype detectors (512-word scan, L2-hot, wave-uniform result).
// ---------------------------------------------------------------------------
__device__ __forceinline__ int detect_f32_block(const unsigned int* __restrict__ w) {
    __shared__ int bfc_s, tot_s;
    if (threadIdx.x == 0) { bfc_s = 0; tot_s = 0; }
    __syncthreads();
    int bfc = 0, tot = 0;
    for (int i = threadIdx.x; i < 512; i += blockDim.x) {
        unsigned v = w[i];
        if (v != 0u) {
            tot++;
            unsigned e = (v >> 7) & 0xFFu;
            if (e >= 100u && e <= 140u) bfc++;
        }
    }
    atomicAdd(&bfc_s, bfc); atomicAdd(&tot_s, tot);
    __syncthreads();
    int r = (2 * bfc_s < tot_s) ? 1 : 0;
    __syncthreads();
    return r;
}

// mask element size: int64 -> 8, int32/fp32 -> 4, int16/bf16 -> 2, byte -> 1
__device__ __forceinline__ int detect_esz_block(const unsigned int* __restrict__ w) {
    __shared__ int ok8s, ok4s, ok2s;
    if (threadIdx.x == 0) { ok8s = 1; ok4s = 1; ok2s = 1; }
    __syncthreads();
    int ok8 = 1, ok4 = 1, ok2 = 1;
    for (int i = threadIdx.x; i < 512; i += blockDim.x) {
        unsigned v = w[i];
        if ((i & 1) && v != 0u) ok8 = 0;
        if (!(v == 0u || v == 1u || v == 0x3F800000u)) ok4 = 0;
        unsigned lo = v & 0xFFFFu, hi = v >> 16;
        if (!((lo == 0u || lo == 1u || lo == 0x3F80u) &&
              (hi == 0u || hi == 1u || hi == 0x3F80u))) ok2 = 0;
    }
    if (!ok8) atomicAnd(&ok8s, 0);
    if (!ok4) atomicAnd(&ok4s, 0);
    if (!ok2) atomicAnd(&ok2s, 0);
    __syncthreads();
    int r = ok8s ? 8 : (ok4s ? 4 : (ok2s ? 2 : 1));
    __syncthreads();
    return r;
}

// ---------------------------------------------------------------------------
// Kernel: convert fp32 (or passthrough bf16) -> bf16, 8 elems/thread.
// ---------------------------------------------------------------------------
__global__ __launch_bounds__(256) void cvt_bf16_kernel(const void* __restrict__ src,
                                                       bf16* __restrict__ dst) {
    const int f32 = detect_f32_block((const unsigned int*)src);
    size_t e = ((size_t)blockIdx.x * 256 + threadIdx.x) * 8;
    bf16x8 v;
    if (f32) {
        const f32x4* S = (const f32x4*)((const float*)src + e);
        f32x4 a = S[0], b = S[1];
        v[0] = (bf16)a[0]; v[1] = (bf16)a[1]; v[2] = (bf16)a[2]; v[3] = (bf16)a[3];
        v[4] = (bf16)b[0]; v[5] = (bf16)b[1]; v[6] = (bf16)b[2]; v[7] = (bf16)b[3];
    } else {
        v = *(const bf16x8*)((const bf16*)src + e);
    }
    *(bf16x8*)&dst[e] = v;
}

// ---------------------------------------------------------------------------
// Kernel 0: canonicalize mask to a 64-key bitmask [B, N, N/64] (u64). 1 MB.
// ---------------------------------------------------------------------------
__global__ __launch_bounds__(256) void mask_bits_kernel(const void* __restrict__ maskp,
                                                        unsigned long long* __restrict__ bm) {
    const int esz = detect_esz_block((const unsigned int*)maskp);  // wave-uniform
    const int lane = threadIdx.x & 63;
    const int wave = threadIdx.x >> 6;
    const long wbase = ((long)blockIdx.x * 4 + wave) * 16;          // first word
    for (int i = 0; i < 16; i++) {
        long w = wbase + i;
        long idx = w * 64 + lane;
        bool mk;
        if (esz == 4)      mk = ((const unsigned int*)maskp)[idx] != 0u;
        else if (esz == 2) mk = ((const unsigned short*)maskp)[idx] != 0;
        else if (esz == 8) mk = ((const unsigned long long*)maskp)[idx] != 0ull;
        else               mk = ((const unsigned char*)maskp)[idx] != 0;
        unsigned long long b = __ballot(mk);
        if (lane == 0) bm[w] = b;
    }
}

// ---------------------------------------------------------------------------
// async 16B global -> LDS copy (direct-to-LDS, no VGPR round-trip).
// LDS dest must be wave-uniform base; HW adds lane*16.
// ---------------------------------------------------------------------------
__device__ __forceinline__ void async_cp16(const bf16* g, bf16* l) {
    __builtin_amdgcn_global_load_lds((const __attribute__((address_space(1))) void*)g,
                                     (__attribute__((address_space(3))) void*)l,
                                     16, 0, 0);
}

// ---------------------------------------------------------------------------
// Fast GEMM core (m97 structure): C[128x128] = A[128xK]*B[128xK]^T, K=1024.
// ---------------------------------------------------------------------------
template<int APERM>
__device__ __forceinline__ void gemm_tile_fast(const bf16* __restrict__ Ap,
                                               const bf16* __restrict__ Bp,
                                               int m0, int n0,
                                               bf16* ldsA, bf16* ldsB,
                                               f32x4 acc[4][4]) {
    const int K = 1024;
    const int tid = threadIdx.x, lane = tid & 63, wave = tid >> 6;
    const int l15 = lane & 15, q4 = lane >> 4;
    const int mw = (wave & 1) * 64, nw = (wave >> 1) * 64;

    #pragma unroll
    for (int i = 0; i < 4; i++)
        #pragma unroll
        for (int j = 0; j < 4; j++) {
            f32x4 z = {0.f, 0.f, 0.f, 0.f};
            acc[i][j] = z;
        }

    const int rA = tid >> 3;          // row within 32-row issue group
    const int colc = (tid & 7) << 3;  // col (elems) within 64-wide tile

    for (int kt = 0; kt < 16; ++kt) {
        __syncthreads();   // prior iter's ds_reads complete before overwrite
        #pragma unroll
        for (int i = 0; i < 4; i++) {
            int r = i * 32 + rA;
            size_t ae;
            if (APERM) {
                int m = m0 + r;
                ae = (((size_t)(m >> 11) * HH + kt) * NN + (m & (NN - 1))) * HD + colc;
            } else {
                ae = (size_t)(m0 + r) * K + kt * 64 + colc;
            }
            async_cp16(&Ap[ae], &ldsA[i * 2048 + wave * 512]);
            size_t be = (size_t)(n0 + r) * K + kt * 64 + colc;
            async_cp16(&Bp[be], &ldsB[i * 2048 + wave * 512]);
        }
        __syncthreads();   // vmcnt(0) drain: staged tile visible to all waves
        #pragma unroll
        for (int ks = 0; ks < 2; ks++) {
            bf16x8 af[4], bfr[4];
            #pragma unroll
            for (int i = 0; i < 4; i++)
                af[i] = *(bf16x8*)&ldsA[(mw + i * 16 + l15) * 64 + ks * 32 + q4 * 8];
            #pragma unroll
            for (int j = 0; j < 4; j++)
                bfr[j] = *(bf16x8*)&ldsB[(nw + j * 16 + l15) * 64 + ks * 32 + q4 * 8];
            #pragma unroll
            for (int i = 0; i < 4; i++)
                #pragma unroll
                for (int j = 0; j < 4; j++)
                    acc[i][j] = MFMA16(af[i], bfr[j], acc[i][j]);
        }
    }
}

// ---------------------------------------------------------------------------
// Legacy GEMM core (register-staged, in-loop fp32->bf16): tier-B qkv only.
// ---------------------------------------------------------------------------
__device__ __forceinline__ void gemm_tile(const void* __restrict__ Ap,
                                          const bf16* __restrict__ Bp,
                                          int K, int m0, int n0,
                                          int af32, int aperm,
                                          bf16* ldsA, bf16* ldsB,
                                          f32x4 acc[4][4]) {
    const int tid = threadIdx.x, lane = tid & 63, wave = tid >> 6;
    const int l15 = lane & 15, q4 = lane >> 4;
    const int mw = (wave & 1) * 64, nw = (wave >> 1) * 64;

    #pragma unroll
    for (int i = 0; i < 4; i++)
        #pragma unroll
        for (int j = 0; j < 4; j++) {
            f32x4 z = {0.f, 0.f, 0.f, 0.f};
            acc[i][j] = z;
        }

    const int nkt = K / 64;
    for (int kt = 0; kt < nkt; ++kt) {
        __syncthreads();
        #pragma unroll
        for (int c0 = 0; c0 < 4; c0++) {
            int c = tid + c0 * 256;               // 1024 chunks of 8 elems
            int r = c >> 3, kc = (c & 7) << 3;
            size_t ae;
            if (aperm) {
                int m = m0 + r;
                ae = (((size_t)(m >> 11) * HH + kt) * NN + (m & (NN - 1))) * HD + kc;
            } else {
                ae = (size_t)(m0 + r) * K + kt * 64 + kc;
            }
            bf16x8 av;
            if (af32) {
                const f32x4* Af = (const f32x4*)((const float*)Ap + ae);
                f32x4 a0 = Af[0], a1 = Af[1];
                av[0] = (bf16)a0[0]; av[1] = (bf16)a0[1]; av[2] = (bf16)a0[2]; av[3] = (bf16)a0[3];
                av[4] = (bf16)a1[0]; av[5] = (bf16)a1[1]; av[6] = (bf16)a1[2]; av[7] = (bf16)a1[3];
            } else {
                av = *(const bf16x8*)((const bf16*)Ap + ae);
            }
            *(bf16x8*)&ldsA[r * 72 + kc] = av;
            size_t be = (size_t)(n0 + r) * K + kt * 64 + kc;
            *(bf16x8*)&ldsB[r * 72 + kc] = *(const bf16x8*)&Bp[be];
        }
        __syncthreads();
        #pragma unroll
        for (int ks = 0; ks < 2; ks++) {
            bf16x8 af[4], bfr[4];
            #pragma unroll
            for (int i = 0; i < 4; i++)
                af[i] = *(bf16x8*)&ldsA[(mw + i * 16 + l15) * 72 + ks * 32 + q4 * 8];
            #pragma unroll
            for (int j = 0; j < 4; j++)
                bfr[j] = *(bf16x8*)&ldsB[(nw + j * 16 + l15) * 72 + ks * 32 + q4 * 8];
            #pragma unroll
            for (int i = 0; i < 4; i++)
                #pragma unroll
                for (int j = 0; j < 4; j++)
                    acc[i][j] = MFMA16(af[i], bfr[j], acc[i][j]);
        }
    }
}

// ---------------------------------------------------------------------------
// Kernel 1a: QKV projection, fast path (A pre-converted to bf16).
// ---------------------------------------------------------------------------
__global__ __launch_bounds__(256, 2) void qkv_fast_kernel(const bf16* __restrict__ X16,
                                                          const bf16* __restrict__ Wqkv,
                                                          bf16* __restrict__ Qb,
                                                          bf16* __restrict__ Kb,
                                                          bf16* __restrict__ Vt) {
    __shared__ alignas(16) bf16 ldsA[128 * 64];
    __shared__ alignas(16) bf16 ldsB[128 * 64];
    f32x4 acc[4][4];
    const int m0 = blockIdx.y * 128, n0 = blockIdx.x * 128;
    gemm_tile_fast<0>(X16, Wqkv, m0, n0, ldsA, ldsB, acc);

    const int tid = threadIdx.x, lane = tid & 63, wave = tid >> 6;
    const int l15 = lane & 15, q4 = lane >> 4;
    const int mw = (wave & 1) * 64, nw = (wave >> 1) * 64;
    #pragma unroll
    for (int i = 0; i < 4; i++) {
        #pragma unroll
        for (int j = 0; j < 4; j++) {
            #pragma unroll
            for (int r = 0; r < 4; r++) {
                int m = m0 + mw + i * 16 + q4 * 4 + r;
                int n = n0 + nw + j * 16 + l15;
                int b = m >> 11, nq = m & 2047;
                int which = n >> 10, cc = n & 1023;
                int h = cc >> 6, d = cc & 63;
                float v = acc[i][j][r];
                size_t bh = (size_t)(b * HH + h);
                if (which == 0)
                    Qb[(bh * NN + nq) * HD + d] = (bf16)(v * QSCALE);
                else if (which == 1)
                    Kb[(bh * NN + nq) * HD + d] = (bf16)v;
                else
                    Vt[(bh * HD + d) * NN + nq] = (bf16)v;
            }
        }
    }
}

// ---------------------------------------------------------------------------
// Kernel 1b: QKV projection, legacy path (fp32/bf16 A, reg staging). Tier B.
// ---------------------------------------------------------------------------
__global__ __launch_bounds__(256, 2) void qkv_kernel(const void* __restrict__ X,
                                                     const bf16* __restrict__ Wqkv,
                                                     bf16* __restrict__ Qb,
                                                     bf16* __restrict__ Kb,
                                                     bf16* __restrict__ Vt) {
    __shared__ alignas(16) bf16 ldsA[128 * 72];
    __shared__ alignas(16) bf16 ldsB[128 * 72];
    const int f32 = detect_f32_block((const unsigned int*)X);
    f32x4 acc[4][4];
    const int m0 = blockIdx.y * 128, n0 = blockIdx.x * 128;
    gemm_tile(X, Wqkv, 1024, m0, n0, f32, 0, ldsA, ldsB, acc);

    const int tid = threadIdx.x, lane = tid & 63, wave = tid >> 6;
    const int l15 = lane & 15, q4 = lane >> 4;
    const int mw = (wave & 1) * 64, nw = (wave >> 1) * 64;
    #pragma unroll
    for (int i = 0; i < 4; i++) {
        #pragma unroll
        for (int j = 0; j < 4; j++) {
            #pragma unroll
            for (int r = 0; r < 4; r++) {
                int m = m0 + mw + i * 16 + q4 * 4 + r;
                int n = n0 + nw + j * 16 + l15;
                int b = m >> 11, nq = m & 2047;
                int which = n >> 10, cc = n & 1023;
                int h = cc >> 6, d = cc & 63;
                float v = acc[i][j][r];
                size_t bh = (size_t)(b * HH + h);
                if (which == 0)
                    Qb[(bh * NN + nq) * HD + d] = (bf16)(v * QSCALE);
                else if (which == 1)
                    Kb[(bh * NN + nq) * HD + d] = (bf16)v;
                else
                    Vt[(bh * HD + d) * NN + nq] = (bf16)v;
            }
        }
    }
}

// ---------------------------------------------------------------------------
// Kernel 2: flash attention v9:
//  - Swapped QK^T: sj = mfma(K, Q) gives S^T per lane — 4 CONSECUTIVE keys
//    (j*16+q4*4+r) for one q-row (l15). P-store becomes 8 ds_write_b64
//    (was 32 ds_write_b16); mask loads 8 -> 2 words/thread/iter; variable
//    shifts 32 -> 4. Same XOR-block swizzle (injective, 8B-aligned); the
//    b128 read side formula is unchanged.
//  - 256-thread blocks (4 waves x 32 q-rows, same K/V amortization), BQ=128,
//    grid 512 = 2 blocks/CU: co-resident blocks overlap MFMA/VALU/DS phases.
//  - Double-buffered Kt/Vs, one barrier/iter; T14 reg prefetch; T5 setprio.
// ---------------------------------------------------------------------------
__global__ __launch_bounds__(256, 2) void attn_kernel(const bf16* __restrict__ Qb,
                                                      const bf16* __restrict__ Kb,
                                                      const bf16* __restrict__ Vt,
                                                      const unsigned long long* __restrict__ bm,
                                                      bf16* __restrict__ Ob) {
    __shared__ alignas(16) bf16 Kt[2][64 * 72];
    __shared__ alignas(16) bf16 Vs[2][64 * 72];    // [d][key], stride 72
    __shared__ alignas(16) bf16 Ps[4][32 * 72];    // per-wave P tile (swizzled)

    // XCD swizzle: 512 blocks; XCD x gets logical blocks [x*64, x*64+64) = 4 bh
    const int wg = blockIdx.y * (NN / 128) + blockIdx.x;   // 512 blocks
    const int swzb = (wg & 7) * 64 + (wg >> 3);            // bijective (512%8==0)
    const int bh = swzb >> 4;
    const int qb = (swzb & 15) * 128;
    const int b = bh >> 4;
    const int tid = threadIdx.x, lane = tid & 63, wave = tid >> 6;
    const int l15 = lane & 15, q4 = lane >> 4;

    const bf16* Qp = Qb + (size_t)bh * NN * HD;
    const bf16* Kp = Kb + (size_t)bh * NN * HD;
    const bf16* Vp = Vt + (size_t)bh * HD * NN;

    // staging geometry: 256 threads x 2 chunks of 8 elems = one 64x64 tile
    const int sr = tid >> 3, skc = (tid & 7) << 3;

    // Q fragments for both 16-row halves: rows qrb + h*16 + l15
    const int qrb = qb + wave * 32;
    bf16x8 qf[2][2];
    #pragma unroll
    for (int h = 0; h < 2; h++)
        #pragma unroll
        for (int s = 0; s < 2; s++)
            qf[h][s] = *(const bf16x8*)&Qp[(size_t)(qrb + h * 16 + l15) * HD + s * 32 + q4 * 8];

    // ones B-fragment for the denominator MFMA
    bf16x8 ones;
    #pragma unroll
    for (int i = 0; i < 8; i++) ones[i] = (bf16)1.0f;

    const f32x4 FZ = {0.f, 0.f, 0.f, 0.f};

    f32x4 o[2][4];
    f32x4 lacc[2] = {FZ, FZ};
    #pragma unroll
    for (int h = 0; h < 2; h++)
        #pragma unroll
        for (int jd = 0; jd < 4; jd++) o[h][jd] = FZ;

    // bitmask: this lane's q-row word (S^T: one q per lane, l15) per half
    const unsigned long long* bmr = bm + ((size_t)b * NN + qrb + l15) * NW;

    bf16* Pw = &Ps[wave][0];
    const int swzP = (l15 >> 1) & 7;          // P block swizzle for this q-row
    const int pwrow = l15 * 72;               // P row base (elems), half adds 16*72

    // ---- prologue prefetch: tile 0 K/V slices + mask words into registers
    bf16x8 kreg[2], vreg[2];
    #pragma unroll
    for (int s2 = 0; s2 < 2; s2++) {
        kreg[s2] = *(const bf16x8*)&Kp[(size_t)(sr + s2 * 32) * HD + skc];
        vreg[s2] = *(const bf16x8*)&Vp[(size_t)(sr + s2 * 32) * NN + skc];
    }
    unsigned long long mwreg[2];
    #pragma unroll
    for (int h = 0; h < 2; h++) mwreg[h] = bmr[(size_t)h * 16 * NW];

    for (int kt = 0; kt < NN / 64; ++kt) {
        bf16* KtC = &Kt[kt & 1][0];
        bf16* VsC = &Vs[kt & 1][0];
        // stage this tile (regs -> LDS); readers of this buffer from iter
        // kt-2 are separated by barrier(kt-1): single barrier per iter safe.
        #pragma unroll
        for (int s2 = 0; s2 < 2; s2++) {
            *(bf16x8*)&KtC[(sr + s2 * 32) * 72 + skc] = kreg[s2];
            *(bf16x8*)&VsC[(sr + s2 * 32) * 72 + skc] = vreg[s2];
        }
        __syncthreads();

        // capture current mask words, pre-shifted for this lane's key group
        unsigned s0[2], s1[2];
        #pragma unroll
        for (int h = 0; h < 2; h++) {
            s0[h] = ((unsigned)mwreg[h]) >> (q4 * 4);
            s1[h] = ((unsigned)(mwreg[h] >> 32)) >> (q4 * 4);
        }

        // ---- T14: issue NEXT tile's global loads now; latency hides under
        //      this tile's MFMA+VALU; consumed at next iter's stage writes.
        {
            const int ktn = (kt + 1) & (NN / 64 - 1);   // kt=31 reloads tile 0 (unused)
            #pragma unroll
            for (int s2 = 0; s2 < 2; s2++) {
                kreg[s2] = *(const bf16x8*)&Kp[(size_t)(ktn * 64 + sr + s2 * 32) * HD + skc];
                vreg[s2] = *(const bf16x8*)&Vp[(size_t)(sr + s2 * 32) * NN + ktn * 64 + skc];
            }
            #pragma unroll
            for (int h = 0; h < 2; h++) mwreg[h] = bmr[(size_t)h * 16 * NW + ktn];
        }

        // S^T = K (Q*scale*log2e)^T : lane holds S[key=j*16+q4*4+r][q=l15]
        f32x4 sj[2][4];
        #pragma unroll
        for (int j = 0; j < 4; j++) {
            bf16x8 kf0 = *(bf16x8*)&KtC[(j * 16 + l15) * 72 + q4 * 8];
            sj[0][j] = MFMA16(kf0, qf[0][0], FZ);
            sj[1][j] = MFMA16(kf0, qf[1][0], FZ);
            bf16x8 kf1 = *(bf16x8*)&KtC[(j * 16 + l15) * 72 + 32 + q4 * 8];
            sj[0][j] = MFMA16(kf1, qf[0][1], sj[0][j]);
            sj[1][j] = MFMA16(kf1, qf[1][1], sj[1][j]);
        }

        // branch-free mask + exp2; pack 4 consecutive keys -> one b64 store.
        // Element key = j*16 + q4*4 + r; mask bit r (j even: s0, odd: >>16).
        #pragma unroll
        for (int h = 0; h < 2; h++) {
            #pragma unroll
            for (int j = 0; j < 4; j++) {
                unsigned w = (j < 2) ? s0[h] : s1[h];
                unsigned ws = (j & 1) ? (w >> 16) : w;
                bf16x4 pv;
                #pragma unroll
                for (int r = 0; r < 4; r++) {
                    unsigned bit = (ws >> r) & 1u;
                    float ex = __builtin_amdgcn_exp2f(sj[h][j][r]);
                    pv[r] = (bf16)(bit ? ex : 0.f);
                }
                const int blk = (2 * j + (q4 >> 1)) ^ swzP;
                *(bf16x4*)&Pw[(h * 16 * 72) + pwrow + blk * 8 + (q4 & 1) * 4] = pv;
            }
        }

        // O += P V ; lacc += P * 1. Each vf read feeds both halves' MFMAs.
        __builtin_amdgcn_s_setprio(1);
        #pragma unroll
        for (int ks = 0; ks < 2; ks++) {
            const int psw = ((4 * ks + q4) ^ swzP) * 8;
            bf16x8 pf0 = *(bf16x8*)&Pw[pwrow + psw];
            bf16x8 pf1 = *(bf16x8*)&Pw[(16 * 72) + pwrow + psw];
            lacc[0] = MFMA16(pf0, ones, lacc[0]);
            lacc[1] = MFMA16(pf1, ones, lacc[1]);
            #pragma unroll
            for (int jd = 0; jd < 4; jd++) {
                bf16x8 vf = *(bf16x8*)&VsC[(jd * 16 + l15) * 72 + ks * 32 + q4 * 8];
                o[0][jd] = MFMA16(pf0, vf, o[0][jd]);
                o[1][jd] = MFMA16(pf1, vf, o[1][jd]);
            }
        }
        __builtin_amdgcn_s_setprio(0);
    }

    // normalize + write (lacc[h][r] = rowsum for row h*16+q4*4+r)
    #pragma unroll
    for (int h = 0; h < 2; h++) {
        float rl[4];
        #pragma unroll
        for (int r = 0; r < 4; r++) rl[r] = 1.0f / lacc[h][r];
        #pragma unroll
        for (int jd = 0; jd < 4; jd++) {
            #pragma unroll
            for (int r = 0; r < 4; r++) {
                int q = qrb + h * 16 + q4 * 4 + r;
                int d = jd * 16 + l15;
                Ob[((size_t)bh * NN + q) * HD + d] = (bf16)(o[h][jd][r] * rl[r]);
            }
        }
    }
}

// ---------------------------------------------------------------------------
// Kernel 3: output projection + bias, fast path (both tiers; A always bf16).
// ---------------------------------------------------------------------------
__global__ __launch_bounds__(256, 2) void proj_fast_kernel(const bf16* __restrict__ Ain,
                                                           const bf16* __restrict__ Wp16,
                                                           const void* __restrict__ biasp,
                                                           void* __restrict__ Outd,
                                                           void* __restrict__ Tmp,
                                                           int direct) {
    __shared__ alignas(16) bf16 ldsA[128 * 64];
    __shared__ alignas(16) bf16 ldsB[128 * 64];
    const int f32 = detect_f32_block((const unsigned int*)biasp);
    f32x4 acc[4][4];
    const int m0 = blockIdx.y * 128, n0 = blockIdx.x * 128;
    gemm_tile_fast<1>(Ain, Wp16, m0, n0, ldsA, ldsB, acc);

    const int tid = threadIdx.x, lane = tid & 63, wave = tid >> 6;
    const int l15 = lane & 15, q4 = lane >> 4;
    const int mw = (wave & 1) * 64, nw = (wave >> 1) * 64;
    #pragma unroll
    for (int i = 0; i < 4; i++) {
        #pragma unroll
        for (int j = 0; j < 4; j++) {
            #pragma unroll
            for (int r = 0; r < 4; r++) {
                int m = m0 + mw + i * 16 + q4 * 4 + r;
                int n = n0 + nw + j * 16 + l15;
                float bv = f32 ? ((const float*)biasp)[n] : (float)((const bf16*)biasp)[n];
                float val = acc[i][j][r] + bv;
                size_t idx = (size_t)m * CC + n;
                if (f32) {
                    if (direct || idx >= (size_t)2097152)   // byte off >= 8MB
                        ((float*)Outd)[idx] = val;
                    else
                        ((float*)Tmp)[idx] = val;
                } else {
                    if (direct) ((bf16*)Outd)[idx] = (bf16)val;
                    else        ((bf16*)Tmp)[idx] = (bf16)val;
                }
            }
        }
    }
}

// ---------------------------------------------------------------------------
// Memory map (fp32 output established => d_out = 16.78 MB):
//  d_out: [0, 8.39M)        Q scratch (tier B: attention O in-place)
//         [8.39M, 14.68M)   W_qkv bf16 (dead after qkv)
//         [14.68M, 15.73M)  key bitmask (dead after attn)
//  ws:    [0, 8.39M)        Kb (tier B: proj low-half staging after attn)
//         [8.39M, 16.78M)   Vt; after attn: Wp16 bf16 (2.1 MB) at 8.39M
//         tier A adds @16.78M: X16 bf16 (dead after qkv) then Ob (attn out)
// ---------------------------------------------------------------------------
extern "C" void kernel_launch(void* const* d_in, const int* in_sizes, int n_in,
                              void* d_out, int out_size, void* d_ws, size_t ws_size,
                              hipStream_t stream) {
    const void* x    = d_in[0];
    const void* mask = d_in[1];
    const void* Wqkv = d_in[2];
    const void* Wp   = d_in[3];
    const void* bias = d_in[4];

    char* ws = (char*)d_ws;
    const size_t QS  = (size_t)BB * HH * NN * HD;     // 4,194,304 elems
    const size_t QSB = QS * sizeof(bf16);             // 8,388,608 bytes
    bf16* Qb   = (bf16*)d_out;
    bf16* W16  = (bf16*)((char*)d_out + QSB);                      // 6.29 MB
    unsigned long long* bm = (unsigned long long*)((char*)d_out + QSB + 3 * CC * CC * 2);
    bf16* Kb   = (bf16*)ws;
    bf16* Vt   = (bf16*)(ws + QSB);
    bf16* Wp16 = (bf16*)(ws + QSB);                                // after attn (Vt dead)

    mask_bits_kernel<<<2048, 256, 0, stream>>>(mask, bm);
    cvt_bf16_kernel<<<3 * CC * CC / (256 * 8), 256, 0, stream>>>(Wqkv, W16);

    if (ws_size >= 3 * QSB) {
        // Fast qkv: pre-convert X to bf16 in the (not-yet-live) Ob slot.
        bf16* X16 = (bf16*)(ws + 2 * QSB);
        cvt_bf16_kernel<<<(BB * NN * CC) / (256 * 8), 256, 0, stream>>>(x, X16);
        qkv_fast_kernel<<<dim3(3072 / 128, 4096 / 128), 256, 0, stream>>>(X16, W16, Qb, Kb, Vt);
        bf16* Ob = (bf16*)(ws + 2 * QSB);   // reuses X16 slot (X16 dead)
        attn_kernel<<<dim3(NN / 128, BB * HH), 256, 0, stream>>>(Qb, Kb, Vt, bm, Ob);
        cvt_bf16_kernel<<<CC * CC / (256 * 8), 256, 0, stream>>>(Wp, Wp16);
        proj_fast_kernel<<<dim3(1024 / 128, 4096 / 128), 256, 0, stream>>>(Ob, Wp16, bias, d_out, d_out, 1);
    } else {
        qkv_kernel<<<dim3(3072 / 128, 4096 / 128), 256, 0, stream>>>(x, W16, Qb, Kb, Vt);
        attn_kernel<<<dim3(NN / 128, BB * HH), 256, 0, stream>>>(Qb, Kb, Vt, bm, Qb);
        cvt_bf16_kernel<<<CC * CC / (256 * 8), 256, 0, stream>>>(Wp, Wp16);
        proj_fast_kernel<<<dim3(1024 / 128, 4096 / 128), 256, 0, stream>>>(Qb, Wp16, bias, d_out, ws, 0);
        hipMemcpyAsync(d_out, ws, QSB, hipMemcpyDeviceToDevice, stream);
    }
}

// Round 6
// 263.919 us; speedup vs baseline: 1.1031x; 1.0570x over previous
//
#include <hip/hip_runtime.h>
#include <hip/hip_bf16.h>

typedef __bf16 bf16;
typedef __bf16 bf16x4 __attribute__((ext_vector_type(4)));
typedef __bf16 bf16x8 __attribute__((ext_vector_type(8)));
typedef float f32x4 __attribute__((ext_vector_type(4)));

#define MFMA16(a, b, c) __builtin_amdgcn_mfma_f32_16x16x32_bf16((a), (b), (c), 0, 0, 0)

// Problem constants
#define BB 2
#define HH 16
#define NN 2048
#define CC 1024
#define HD 64
#define NW (NN / 64)   // 64-key words per row = 32

// Q pre-scale: HD^-0.5 * log2(e), so attention can use exp2 directly.
#define QSCALE 0.1803368867f

// ---------------------------------------------------------------------------
// Per-block dtype detectors (512-word scan, L2-hot, wave-uniform result).
// ---------------------------------------------------------------------------
__device__ __forceinline__ int detect_f32_block(const unsigned int* __restrict__ w) {
    __shared__ int bfc_s, tot_s;
    if (threadIdx.x == 0) { bfc_s = 0; tot_s = 0; }
    __syncthreads();
    int bfc = 0, tot = 0;
    for (int i = threadIdx.x; i < 512; i += blockDim.x) {
        unsigned v = w[i];
        if (v != 0u) {
            tot++;
            unsigned e = (v >> 7) & 0xFFu;
            if (e >= 100u && e <= 140u) bfc++;
        }
    }
    atomicAdd(&bfc_s, bfc); atomicAdd(&tot_s, tot);
    __syncthreads();
    int r = (2 * bfc_s < tot_s) ? 1 : 0;
    __syncthreads();
    return r;
}

// mask element size: int64 -> 8, int32/fp32 -> 4, int16/bf16 -> 2, byte -> 1
__device__ __forceinline__ int detect_esz_block(const unsigned int* __restrict__ w) {
    __shared__ int ok8s, ok4s, ok2s;
    if (threadIdx.x == 0) { ok8s = 1; ok4s = 1; ok2s = 1; }
    __syncthreads();
    int ok8 = 1, ok4 = 1, ok2 = 1;
    for (int i = threadIdx.x; i < 512; i += blockDim.x) {
        unsigned v = w[i];
        if ((i & 1) && v != 0u) ok8 = 0;
        if (!(v == 0u || v == 1u || v == 0x3F800000u)) ok4 = 0;
        unsigned lo = v & 0xFFFFu, hi = v >> 16;
        if (!((lo == 0u || lo == 1u || lo == 0x3F80u) &&
              (hi == 0u || hi == 1u || hi == 0x3F80u))) ok2 = 0;
    }
    if (!ok8) atomicAnd(&ok8s, 0);
    if (!ok4) atomicAnd(&ok4s, 0);
    if (!ok2) atomicAnd(&ok2s, 0);
    __syncthreads();
    int r = ok8s ? 8 : (ok4s ? 4 : (ok2s ? 2 : 1));
    __syncthreads();
    return r;
}

// 8-elem fp32->bf16 (or passthrough) convert
__device__ __forceinline__ void cvt8(const void* __restrict__ src, bf16* __restrict__ dst,
                                     size_t e, int f32) {
    bf16x8 v;
    if (f32) {
        const f32x4* S = (const f32x4*)((const float*)src + e);
        f32x4 a = S[0], b = S[1];
        v[0] = (bf16)a[0]; v[1] = (bf16)a[1]; v[2] = (bf16)a[2]; v[3] = (bf16)a[3];
        v[4] = (bf16)b[0]; v[5] = (bf16)b[1]; v[6] = (bf16)b[2]; v[7] = (bf16)b[3];
    } else {
        v = *(const bf16x8*)((const bf16*)src + e);
    }
    *(bf16x8*)&dst[e] = v;
}

// ---------------------------------------------------------------------------
// Kernel: standalone convert (used for Wp after attn frees its slot).
// ---------------------------------------------------------------------------
__global__ __launch_bounds__(256) void cvt_bf16_kernel(const void* __restrict__ src,
                                                       bf16* __restrict__ dst) {
    const int f32 = detect_f32_block((const unsigned int*)src);
    size_t e = ((size_t)blockIdx.x * 256 + threadIdx.x) * 8;
    cvt8(src, dst, e, f32);
}

// ---------------------------------------------------------------------------
// Fused prep kernel: [0,2048) mask->bitmask; [2048,3584) Wqkv cvt;
// [3584,5632) X cvt (tier A only — grid size selects).
// All three regions are independent (disjoint inputs/outputs).
// ---------------------------------------------------------------------------
__global__ __launch_bounds__(256) void prep_kernel(const void* __restrict__ maskp,
                                                   unsigned long long* __restrict__ bm,
                                                   const void* __restrict__ Wqkv,
                                                   bf16* __restrict__ W16,
                                                   const void* __restrict__ x,
                                                   bf16* __restrict__ X16) {
    const int bid = blockIdx.x;
    if (bid < 2048) {
        const int esz = detect_esz_block((const unsigned int*)maskp);  // wave-uniform
        const int lane = threadIdx.x & 63;
        const int wave = threadIdx.x >> 6;
        const long wbase = ((long)bid * 4 + wave) * 16;
        for (int i = 0; i < 16; i++) {
            long w = wbase + i;
            long idx = w * 64 + lane;
            bool mk;
            if (esz == 4)      mk = ((const unsigned int*)maskp)[idx] != 0u;
            else if (esz == 2) mk = ((const unsigned short*)maskp)[idx] != 0;
            else if (esz == 8) mk = ((const unsigned long long*)maskp)[idx] != 0ull;
            else               mk = ((const unsigned char*)maskp)[idx] != 0;
            unsigned long long b = __ballot(mk);
            if (lane == 0) bm[w] = b;
        }
    } else if (bid < 3584) {
        const int f32 = detect_f32_block((const unsigned int*)Wqkv);
        size_t e = ((size_t)(bid - 2048) * 256 + threadIdx.x) * 8;
        cvt8(Wqkv, W16, e, f32);
    } else {
        const int f32 = detect_f32_block((const unsigned int*)x);
        size_t e = ((size_t)(bid - 3584) * 256 + threadIdx.x) * 8;
        cvt8(x, X16, e, f32);
    }
}

// ---------------------------------------------------------------------------
// async 16B global -> LDS copy (direct-to-LDS, no VGPR round-trip).
// LDS dest must be wave-uniform base; HW adds lane*16.
// ---------------------------------------------------------------------------
__device__ __forceinline__ void async_cp16(const bf16* g, bf16* l) {
    __builtin_amdgcn_global_load_lds((const __attribute__((address_space(1))) void*)g,
                                     (__attribute__((address_space(3))) void*)l,
                                     16, 0, 0);
}

// ---------------------------------------------------------------------------
// Fast GEMM core (m97 structure): C[128x128] = A[128xK]*B[128xK]^T, K=1024.
// ---------------------------------------------------------------------------
template<int APERM>
__device__ __forceinline__ void gemm_tile_fast(const bf16* __restrict__ Ap,
                                               const bf16* __restrict__ Bp,
                                               int m0, int n0,
                                               bf16* ldsA, bf16* ldsB,
                                               f32x4 acc[4][4]) {
    const int K = 1024;
    const int tid = threadIdx.x, lane = tid & 63, wave = tid >> 6;
    const int l15 = lane & 15, q4 = lane >> 4;
    const int mw = (wave & 1) * 64, nw = (wave >> 1) * 64;

    #pragma unroll
    for (int i = 0; i < 4; i++)
        #pragma unroll
        for (int j = 0; j < 4; j++) {
            f32x4 z = {0.f, 0.f, 0.f, 0.f};
            acc[i][j] = z;
        }

    const int rA = tid >> 3;          // row within 32-row issue group
    const int colc = (tid & 7) << 3;  // col (elems) within 64-wide tile

    for (int kt = 0; kt < 16; ++kt) {
        __syncthreads();   // prior iter's ds_reads complete before overwrite
        #pragma unroll
        for (int i = 0; i < 4; i++) {
            int r = i * 32 + rA;
            size_t ae;
            if (APERM) {
                int m = m0 + r;
                ae = (((size_t)(m >> 11) * HH + kt) * NN + (m & (NN - 1))) * HD + colc;
            } else {
                ae = (size_t)(m0 + r) * K + kt * 64 + colc;
            }
            async_cp16(&Ap[ae], &ldsA[i * 2048 + wave * 512]);
            size_t be = (size_t)(n0 + r) * K + kt * 64 + colc;
            async_cp16(&Bp[be], &ldsB[i * 2048 + wave * 512]);
        }
        __syncthreads();   // vmcnt(0) drain: staged tile visible to all waves
        #pragma unroll
        for (int ks = 0; ks < 2; ks++) {
            bf16x8 af[4], bfr[4];
            #pragma unroll
            for (int i = 0; i < 4; i++)
                af[i] = *(bf16x8*)&ldsA[(mw + i * 16 + l15) * 64 + ks * 32 + q4 * 8];
            #pragma unroll
            for (int j = 0; j < 4; j++)
                bfr[j] = *(bf16x8*)&ldsB[(nw + j * 16 + l15) * 64 + ks * 32 + q4 * 8];
            #pragma unroll
            for (int i = 0; i < 4; i++)
                #pragma unroll
                for (int j = 0; j < 4; j++)
                    acc[i][j] = MFMA16(af[i], bfr[j], acc[i][j]);
        }
    }
}

// ---------------------------------------------------------------------------
// Legacy GEMM core (register-staged, in-loop fp32->bf16): tier-B qkv only.
// ---------------------------------------------------------------------------
__device__ __forceinline__ void gemm_tile(const void* __restrict__ Ap,
                                          const bf16* __restrict__ Bp,
                                          int K, int m0, int n0,
                                          int af32, int aperm,
                                          bf16* ldsA, bf16* ldsB,
                                          f32x4 acc[4][4]) {
    const int tid = threadIdx.x, lane = tid & 63, wave = tid >> 6;
    const int l15 = lane & 15, q4 = lane >> 4;
    const int mw = (wave & 1) * 64, nw = (wave >> 1) * 64;

    #pragma unroll
    for (int i = 0; i < 4; i++)
        #pragma unroll
        for (int j = 0; j < 4; j++) {
            f32x4 z = {0.f, 0.f, 0.f, 0.f};
            acc[i][j] = z;
        }

    const int nkt = K / 64;
    for (int kt = 0; kt < nkt; ++kt) {
        __syncthreads();
        #pragma unroll
        for (int c0 = 0; c0 < 4; c0++) {
            int c = tid + c0 * 256;               // 1024 chunks of 8 elems
            int r = c >> 3, kc = (c & 7) << 3;
            size_t ae;
            if (aperm) {
                int m = m0 + r;
                ae = (((size_t)(m >> 11) * HH + kt) * NN + (m & (NN - 1))) * HD + kc;
            } else {
                ae = (size_t)(m0 + r) * K + kt * 64 + kc;
            }
            bf16x8 av;
            if (af32) {
                const f32x4* Af = (const f32x4*)((const float*)Ap + ae);
                f32x4 a0 = Af[0], a1 = Af[1];
                av[0] = (bf16)a0[0]; av[1] = (bf16)a0[1]; av[2] = (bf16)a0[2]; av[3] = (bf16)a0[3];
                av[4] = (bf16)a1[0]; av[5] = (bf16)a1[1]; av[6] = (bf16)a1[2]; av[7] = (bf16)a1[3];
            } else {
                av = *(const bf16x8*)((const bf16*)Ap + ae);
            }
            *(bf16x8*)&ldsA[r * 72 + kc] = av;
            size_t be = (size_t)(n0 + r) * K + kt * 64 + kc;
            *(bf16x8*)&ldsB[r * 72 + kc] = *(const bf16x8*)&Bp[be];
        }
        __syncthreads();
        #pragma unroll
        for (int ks = 0; ks < 2; ks++) {
            bf16x8 af[4], bfr[4];
            #pragma unroll
            for (int i = 0; i < 4; i++)
                af[i] = *(bf16x8*)&ldsA[(mw + i * 16 + l15) * 72 + ks * 32 + q4 * 8];
            #pragma unroll
            for (int j = 0; j < 4; j++)
                bfr[j] = *(bf16x8*)&ldsB[(nw + j * 16 + l15) * 72 + ks * 32 + q4 * 8];
            #pragma unroll
            for (int i = 0; i < 4; i++)
                #pragma unroll
                for (int j = 0; j < 4; j++)
                    acc[i][j] = MFMA16(af[i], bfr[j], acc[i][j]);
        }
    }
}

// ---------------------------------------------------------------------------
// Shared QKV epilogue. 'which' is block-uniform (n0 multiple of 128).
// V blocks pack 4 consecutive-m values into one b64 store (Vt is [d][n]:
// scalar stores were 2B pieces 8B apart — 4x the insts and transactions).
// ---------------------------------------------------------------------------
__device__ __forceinline__ void qkv_epilogue(f32x4 acc[4][4], int m0, int n0,
                                             bf16* __restrict__ Qb,
                                             bf16* __restrict__ Kb,
                                             bf16* __restrict__ Vt) {
    const int tid = threadIdx.x, lane = tid & 63, wave = tid >> 6;
    const int l15 = lane & 15, q4 = lane >> 4;
    const int mw = (wave & 1) * 64, nw = (wave >> 1) * 64;

    if (n0 >= 2 * CC) {
        // V region: packed bf16x4 stores along nq
        #pragma unroll
        for (int i = 0; i < 4; i++) {
            #pragma unroll
            for (int j = 0; j < 4; j++) {
                int n = n0 - 2 * CC + nw + j * 16 + l15;   // 0..1023
                int h = n >> 6, d = n & 63;
                int mbase = m0 + mw + i * 16 + q4 * 4;     // 4 consecutive m, no 2048-cross
                int b = mbase >> 11, nq = mbase & (NN - 1);
                bf16x4 pv;
                #pragma unroll
                for (int r = 0; r < 4; r++) pv[r] = (bf16)acc[i][j][r];
                *(bf16x4*)&Vt[((size_t)(b * HH + h) * HD + d) * NN + nq] = pv;
            }
        }
    } else {
        const int isK = n0 >= CC;
        #pragma unroll
        for (int i = 0; i < 4; i++) {
            #pragma unroll
            for (int j = 0; j < 4; j++) {
                #pragma unroll
                for (int r = 0; r < 4; r++) {
                    int m = m0 + mw + i * 16 + q4 * 4 + r;
                    int n = (n0 & (CC - 1)) + nw + j * 16 + l15;
                    int h = n >> 6, d = n & 63;
                    int b = m >> 11, nq = m & (NN - 1);
                    size_t bh = (size_t)(b * HH + h);
                    float v = acc[i][j][r];
                    if (isK) Kb[(bh * NN + nq) * HD + d] = (bf16)v;
                    else     Qb[(bh * NN + nq) * HD + d] = (bf16)(v * QSCALE);
                }
            }
        }
    }
}

// ---------------------------------------------------------------------------
// Kernel 1a: QKV projection, fast path (A pre-converted to bf16).
// ---------------------------------------------------------------------------
__global__ __launch_bounds__(256, 2) void qkv_fast_kernel(const bf16* __restrict__ X16,
                                                          const bf16* __restrict__ Wqkv,
                                                          bf16* __restrict__ Qb,
                                                          bf16* __restrict__ Kb,
                                                          bf16* __restrict__ Vt) {
    __shared__ alignas(16) bf16 ldsA[128 * 64];
    __shared__ alignas(16) bf16 ldsB[128 * 64];
    f32x4 acc[4][4];
    const int m0 = blockIdx.y * 128, n0 = blockIdx.x * 128;
    gemm_tile_fast<0>(X16, Wqkv, m0, n0, ldsA, ldsB, acc);
    qkv_epilogue(acc, m0, n0, Qb, Kb, Vt);
}

// ---------------------------------------------------------------------------
// Kernel 1b: QKV projection, legacy path (fp32/bf16 A, reg staging). Tier B.
// ---------------------------------------------------------------------------
__global__ __launch_bounds__(256, 2) void qkv_kernel(const void* __restrict__ X,
                                                     const bf16* __restrict__ Wqkv,
                                                     bf16* __restrict__ Qb,
                                                     bf16* __restrict__ Kb,
                                                     bf16* __restrict__ Vt) {
    __shared__ alignas(16) bf16 ldsA[128 * 72];
    __shared__ alignas(16) bf16 ldsB[128 * 72];
    const int f32 = detect_f32_block((const unsigned int*)X);
    f32x4 acc[4][4];
    const int m0 = blockIdx.y * 128, n0 = blockIdx.x * 128;
    gemm_tile(X, Wqkv, 1024, m0, n0, f32, 0, ldsA, ldsB, acc);
    qkv_epilogue(acc, m0, n0, Qb, Kb, Vt);
}

// ---------------------------------------------------------------------------
// Kernel 2: flash attention v9 (unchanged from R5 measurement).
// ---------------------------------------------------------------------------
__global__ __launch_bounds__(256, 2) void attn_kernel(const bf16* __restrict__ Qb,
                                                      const bf16* __restrict__ Kb,
                                                      const bf16* __restrict__ Vt,
                                                      const unsigned long long* __restrict__ bm,
                                                      bf16* __restrict__ Ob) {
    __shared__ alignas(16) bf16 Kt[2][64 * 72];
    __shared__ alignas(16) bf16 Vs[2][64 * 72];    // [d][key], stride 72
    __shared__ alignas(16) bf16 Ps[4][32 * 72];    // per-wave P tile (swizzled)

    // XCD swizzle: 512 blocks; XCD x gets logical blocks [x*64, x*64+64) = 4 bh
    const int wg = blockIdx.y * (NN / 128) + blockIdx.x;   // 512 blocks
    const int swzb = (wg & 7) * 64 + (wg >> 3);            // bijective (512%8==0)
    const int bh = swzb >> 4;
    const int qb = (swzb & 15) * 128;
    const int b = bh >> 4;
    const int tid = threadIdx.x, lane = tid & 63, wave = tid >> 6;
    const int l15 = lane & 15, q4 = lane >> 4;

    const bf16* Qp = Qb + (size_t)bh * NN * HD;
    const bf16* Kp = Kb + (size_t)bh * NN * HD;
    const bf16* Vp = Vt + (size_t)bh * HD * NN;

    // staging geometry: 256 threads x 2 chunks of 8 elems = one 64x64 tile
    const int sr = tid >> 3, skc = (tid & 7) << 3;

    // Q fragments for both 16-row halves: rows qrb + h*16 + l15
    const int qrb = qb + wave * 32;
    bf16x8 qf[2][2];
    #pragma unroll
    for (int h = 0; h < 2; h++)
        #pragma unroll
        for (int s = 0; s < 2; s++)
            qf[h][s] = *(const bf16x8*)&Qp[(size_t)(qrb + h * 16 + l15) * HD + s * 32 + q4 * 8];

    // ones B-fragment for the denominator MFMA
    bf16x8 ones;
    #pragma unroll
    for (int i = 0; i < 8; i++) ones[i] = (bf16)1.0f;

    const f32x4 FZ = {0.f, 0.f, 0.f, 0.f};

    f32x4 o[2][4];
    f32x4 lacc[2] = {FZ, FZ};
    #pragma unroll
    for (int h = 0; h < 2; h++)
        #pragma unroll
        for (int jd = 0; jd < 4; jd++) o[h][jd] = FZ;

    // bitmask: this lane's q-row word (S^T: one q per lane, l15) per half
    const unsigned long long* bmr = bm + ((size_t)b * NN + qrb + l15) * NW;

    bf16* Pw = &Ps[wave][0];
    const int swzP = (l15 >> 1) & 7;          // P block swizzle for this q-row
    const int pwrow = l15 * 72;               // P row base (elems), half adds 16*72

    // ---- prologue prefetch: tile 0 K/V slices + mask words into registers
    bf16x8 kreg[2], vreg[2];
    #pragma unroll
    for (int s2 = 0; s2 < 2; s2++) {
        kreg[s2] = *(const bf16x8*)&Kp[(size_t)(sr + s2 * 32) * HD + skc];
        vreg[s2] = *(const bf16x8*)&Vp[(size_t)(sr + s2 * 32) * NN + skc];
    }
    unsigned long long mwreg[2];
    #pragma unroll
    for (int h = 0; h < 2; h++) mwreg[h] = bmr[(size_t)h * 16 * NW];

    for (int kt = 0; kt < NN / 64; ++kt) {
        bf16* KtC = &Kt[kt & 1][0];
        bf16* VsC = &Vs[kt & 1][0];
        // stage this tile (regs -> LDS); readers of this buffer from iter
        // kt-2 are separated by barrier(kt-1): single barrier per iter safe.
        #pragma unroll
        for (int s2 = 0; s2 < 2; s2++) {
            *(bf16x8*)&KtC[(sr + s2 * 32) * 72 + skc] = kreg[s2];
            *(bf16x8*)&VsC[(sr + s2 * 32) * 72 + skc] = vreg[s2];
        }
        __syncthreads();

        // capture current mask words, pre-shifted for this lane's key group
        unsigned s0[2], s1[2];
        #pragma unroll
        for (int h = 0; h < 2; h++) {
            s0[h] = ((unsigned)mwreg[h]) >> (q4 * 4);
            s1[h] = ((unsigned)(mwreg[h] >> 32)) >> (q4 * 4);
        }

        // ---- T14: issue NEXT tile's global loads now; latency hides under
        //      this tile's MFMA+VALU; consumed at next iter's stage writes.
        {
            const int ktn = (kt + 1) & (NN / 64 - 1);   // kt=31 reloads tile 0 (unused)
            #pragma unroll
            for (int s2 = 0; s2 < 2; s2++) {
                kreg[s2] = *(const bf16x8*)&Kp[(size_t)(ktn * 64 + sr + s2 * 32) * HD + skc];
                vreg[s2] = *(const bf16x8*)&Vp[(size_t)(sr + s2 * 32) * NN + ktn * 64 + skc];
            }
            #pragma unroll
            for (int h = 0; h < 2; h++) mwreg[h] = bmr[(size_t)h * 16 * NW + ktn];
        }

        // S^T = K (Q*scale*log2e)^T : lane holds S[key=j*16+q4*4+r][q=l15]
        f32x4 sj[2][4];
        #pragma unroll
        for (int j = 0; j < 4; j++) {
            bf16x8 kf0 = *(bf16x8*)&KtC[(j * 16 + l15) * 72 + q4 * 8];
            sj[0][j] = MFMA16(kf0, qf[0][0], FZ);
            sj[1][j] = MFMA16(kf0, qf[1][0], FZ);
            bf16x8 kf1 = *(bf16x8*)&KtC[(j * 16 + l15) * 72 + 32 + q4 * 8];
            sj[0][j] = MFMA16(kf1, qf[0][1], sj[0][j]);
            sj[1][j] = MFMA16(kf1, qf[1][1], sj[1][j]);
        }

        // branch-free mask + exp2; pack 4 consecutive keys -> one b64 store.
        // Element key = j*16 + q4*4 + r; mask bit r (j even: s0, odd: >>16).
        #pragma unroll
        for (int h = 0; h < 2; h++) {
            #pragma unroll
            for (int j = 0; j < 4; j++) {
                unsigned w = (j < 2) ? s0[h] : s1[h];
                unsigned ws = (j & 1) ? (w >> 16) : w;
                bf16x4 pv;
                #pragma unroll
                for (int r = 0; r < 4; r++) {
                    unsigned bit = (ws >> r) & 1u;
                    float ex = __builtin_amdgcn_exp2f(sj[h][j][r]);
                    pv[r] = (bf16)(bit ? ex : 0.f);
                }
                const int blk = (2 * j + (q4 >> 1)) ^ swzP;
                *(bf16x4*)&Pw[(h * 16 * 72) + pwrow + blk * 8 + (q4 & 1) * 4] = pv;
            }
        }

        // O += P V ; lacc += P * 1. Each vf read feeds both halves' MFMAs.
        __builtin_amdgcn_s_setprio(1);
        #pragma unroll
        for (int ks = 0; ks < 2; ks++) {
            const int psw = ((4 * ks + q4) ^ swzP) * 8;
            bf16x8 pf0 = *(bf16x8*)&Pw[pwrow + psw];
            bf16x8 pf1 = *(bf16x8*)&Pw[(16 * 72) + pwrow + psw];
            lacc[0] = MFMA16(pf0, ones, lacc[0]);
            lacc[1] = MFMA16(pf1, ones, lacc[1]);
            #pragma unroll
            for (int jd = 0; jd < 4; jd++) {
                bf16x8 vf = *(bf16x8*)&VsC[(jd * 16 + l15) * 72 + ks * 32 + q4 * 8];
                o[0][jd] = MFMA16(pf0, vf, o[0][jd]);
                o[1][jd] = MFMA16(pf1, vf, o[1][jd]);
            }
        }
        __builtin_amdgcn_s_setprio(0);
    }

    // normalize + write (lacc[h][r] = rowsum for row h*16+q4*4+r)
    #pragma unroll
    for (int h = 0; h < 2; h++) {
        float rl[4];
        #pragma unroll
        for (int r = 0; r < 4; r++) rl[r] = 1.0f / lacc[h][r];
        #pragma unroll
        for (int jd = 0; jd < 4; jd++) {
            #pragma unroll
            for (int r = 0; r < 4; r++) {
                int q = qrb + h * 16 + q4 * 4 + r;
                int d = jd * 16 + l15;
                Ob[((size_t)bh * NN + q) * HD + d] = (bf16)(o[h][jd][r] * rl[r]);
            }
        }
    }
}

// ---------------------------------------------------------------------------
// Kernel 3: output projection + bias, fast path (both tiers; A always bf16).
// ---------------------------------------------------------------------------
__global__ __launch_bounds__(256, 2) void proj_fast_kernel(const bf16* __restrict__ Ain,
                                                           const bf16* __restrict__ Wp16,
                                                           const void* __restrict__ biasp,
                                                           void* __restrict__ Outd,
                                                           void* __restrict__ Tmp,
                                                           int direct) {
    __shared__ alignas(16) bf16 ldsA[128 * 64];
    __shared__ alignas(16) bf16 ldsB[128 * 64];
    const int f32 = detect_f32_block((const unsigned int*)biasp);
    f32x4 acc[4][4];
    const int m0 = blockIdx.y * 128, n0 = blockIdx.x * 128;
    gemm_tile_fast<1>(Ain, Wp16, m0, n0, ldsA, ldsB, acc);

    const int tid = threadIdx.x, lane = tid & 63, wave = tid >> 6;
    const int l15 = lane & 15, q4 = lane >> 4;
    const int mw = (wave & 1) * 64, nw = (wave >> 1) * 64;
    #pragma unroll
    for (int i = 0; i < 4; i++) {
        #pragma unroll
        for (int j = 0; j < 4; j++) {
            #pragma unroll
            for (int r = 0; r < 4; r++) {
                int m = m0 + mw + i * 16 + q4 * 4 + r;
                int n = n0 + nw + j * 16 + l15;
                float bv = f32 ? ((const float*)biasp)[n] : (float)((const bf16*)biasp)[n];
                float val = acc[i][j][r] + bv;
                size_t idx = (size_t)m * CC + n;
                if (f32) {
                    if (direct || idx >= (size_t)2097152)   // byte off >= 8MB
                        ((float*)Outd)[idx] = val;
                    else
                        ((float*)Tmp)[idx] = val;
                } else {
                    if (direct) ((bf16*)Outd)[idx] = (bf16)val;
                    else        ((bf16*)Tmp)[idx] = (bf16)val;
                }
            }
        }
    }
}

// ---------------------------------------------------------------------------
// Memory map (fp32 output established => d_out = 16.78 MB):
//  d_out: [0, 8.39M)        Q scratch (tier B: attention O in-place)
//         [8.39M, 14.68M)   W_qkv bf16 (dead after qkv)
//         [14.68M, 15.73M)  key bitmask (dead after attn)
//  ws:    [0, 8.39M)        Kb (tier B: proj low-half staging after attn)
//         [8.39M, 16.78M)   Vt; after attn: Wp16 bf16 (2.1 MB) at 8.39M
//         tier A adds @16.78M: X16 bf16 (dead after qkv) then Ob (attn out)
// ---------------------------------------------------------------------------
extern "C" void kernel_launch(void* const* d_in, const int* in_sizes, int n_in,
                              void* d_out, int out_size, void* d_ws, size_t ws_size,
                              hipStream_t stream) {
    const void* x    = d_in[0];
    const void* mask = d_in[1];
    const void* Wqkv = d_in[2];
    const void* Wp   = d_in[3];
    const void* bias = d_in[4];

    char* ws = (char*)d_ws;
    const size_t QS  = (size_t)BB * HH * NN * HD;     // 4,194,304 elems
    const size_t QSB = QS * sizeof(bf16);             // 8,388,608 bytes
    bf16* Qb   = (bf16*)d_out;
    bf16* W16  = (bf16*)((char*)d_out + QSB);                      // 6.29 MB
    unsigned long long* bm = (unsigned long long*)((char*)d_out + QSB + 3 * CC * CC * 2);
    bf16* Kb   = (bf16*)ws;
    bf16* Vt   = (bf16*)(ws + QSB);
    bf16* Wp16 = (bf16*)(ws + QSB);                                // after attn (Vt dead)

    if (ws_size >= 3 * QSB) {
        // Fast path: fused prep (mask bits + Wqkv cvt + X cvt into Ob slot).
        bf16* X16 = (bf16*)(ws + 2 * QSB);
        prep_kernel<<<5632, 256, 0, stream>>>(mask, bm, Wqkv, W16, x, X16);
        qkv_fast_kernel<<<dim3(3072 / 128, 4096 / 128), 256, 0, stream>>>(X16, W16, Qb, Kb, Vt);
        bf16* Ob = (bf16*)(ws + 2 * QSB);   // reuses X16 slot (X16 dead)
        attn_kernel<<<dim3(NN / 128, BB * HH), 256, 0, stream>>>(Qb, Kb, Vt, bm, Ob);
        cvt_bf16_kernel<<<CC * CC / (256 * 8), 256, 0, stream>>>(Wp, Wp16);
        proj_fast_kernel<<<dim3(1024 / 128, 4096 / 128), 256, 0, stream>>>(Ob, Wp16, bias, d_out, d_out, 1);
    } else {
        prep_kernel<<<3584, 256, 0, stream>>>(mask, bm, Wqkv, W16, x, (bf16*)ws);  // X region not launched
        qkv_kernel<<<dim3(3072 / 128, 4096 / 128), 256, 0, stream>>>(x, W16, Qb, Kb, Vt);
        attn_kernel<<<dim3(NN / 128, BB * HH), 256, 0, stream>>>(Qb, Kb, Vt, bm, Qb);
        cvt_bf16_kernel<<<CC * CC / (256 * 8), 256, 0, stream>>>(Wp, Wp16);
        proj_fast_kernel<<<dim3(1024 / 128, 4096 / 128), 256, 0, stream>>>(Qb, Wp16, bias, d_out, ws, 0);
        hipMemcpyAsync(d_out, ws, QSB, hipMemcpyDeviceToDevice, stream);
    }
}